// Round 9
// baseline (166.957 us; speedup 1.0000x reference)
//
#include <hip/hip_runtime.h>
#include <stdint.h>
#include <stddef.h>

// Problem constants (fixed by setup_inputs)
#define NB   2      // batch
#define NL   2048   // seq len
#define ND   512    // model dim
#define NH   8      // heads
#define DH   64     // dim head
#define LOG2E 1.44269504f
#define RG_TOT 32768  // NB*NH*NL rows of partials
#define JS   4      // split-j factor

typedef __attribute__((ext_vector_type(8))) short bf16x8;
typedef __attribute__((ext_vector_type(4))) float f32x4;

__device__ __forceinline__ unsigned short f2bf(float f) {
  union { float f; unsigned int u; } c; c.f = f;
  unsigned int u = c.u;
  unsigned int r = u + 0x7fffu + ((u >> 16) & 1u);
  return (unsigned short)(r >> 16);
}

__device__ __forceinline__ float bf2f(unsigned short u) {
  union { unsigned int i; float f; } c; c.i = ((unsigned int)u) << 16; return c.f;
}

// hi/lo bf16 split: hi+lo == v to ~2^-18 relative
__device__ __forceinline__ void split2(float v, unsigned short& h, unsigned short& l) {
  h = f2bf(v);
  l = f2bf(v - bf2f(h));
}

__device__ __forceinline__ float fexp2(float x) {
#if __has_builtin(__builtin_amdgcn_exp2f)
  return __builtin_amdgcn_exp2f(x);
#else
  return exp2f(x);
#endif
}

// async global->LDS 16B copy; lanes of a wave must target base + lane*16
__device__ __forceinline__ void gl_lds16(const unsigned short* g, unsigned short* l) {
#if __has_builtin(__builtin_amdgcn_global_load_lds)
  __builtin_amdgcn_global_load_lds(
      (const __attribute__((address_space(1))) unsigned int*)g,
      (__attribute__((address_space(3))) unsigned int*)l, 16, 0, 0);
#else
  *(uint4*)l = *(const uint4*)g;
#endif
}

// ---------------------------------------------------------------------------
// f32 -> bf16 conversion for x, w_qkv, w_out + zero-padded positions buffer
// ---------------------------------------------------------------------------
#define XC  524288   // 4096*512/4
#define WQC 196608   // 1536*512/4
#define WOC 65536    // 512*512/4
#define TOTC (XC + WQC + WOC)
__global__ void cvt_f32_bf16(const float* __restrict__ x, const float* __restrict__ wq,
                             const float* __restrict__ wo, const float* __restrict__ positions,
                             const int* __restrict__ ns_p,
                             unsigned short* __restrict__ xb, unsigned short* __restrict__ wqb,
                             unsigned short* __restrict__ wob, float* __restrict__ pospad) {
  int idx = blockIdx.x * 256 + threadIdx.x;
  if (idx < TOTC) {
    const float* src; unsigned short* dst; int off;
    if (idx < XC)            { src = x;  dst = xb;  off = idx; }
    else if (idx < XC + WQC) { src = wq; dst = wqb; off = idx - XC; }
    else                     { src = wo; dst = wob; off = idx - XC - WQC; }
    float4 f = ((const float4*)src)[off];
    ushort4 o;
    o.x = f2bf(f.x); o.y = f2bf(f.y); o.z = f2bf(f.z); o.w = f2bf(f.w);
    ((ushort4*)dst)[off] = o;
  } else {
    int i2 = idx - TOTC;
    if (i2 < NB * 1024) {
      int b = i2 >> 10;
      int jj = (i2 & 1023) * 2;
      int Ls = ns_p[0];
      float4 o = make_float4(0.f, 0.f, 0.f, 0.f);
      if (jj < Ls) { o.x = positions[((size_t)b * Ls + jj) * 2];
                     o.y = positions[((size_t)b * Ls + jj) * 2 + 1]; }
      if (jj + 1 < Ls) { o.z = positions[((size_t)b * Ls + jj + 1) * 2];
                         o.w = positions[((size_t)b * Ls + jj + 1) * 2 + 1]; }
      *(float4*)&pospad[((size_t)b * NL + jj) * 2] = o;
    }
  }
}

// ---------------------------------------------------------------------------
// QKV GEMM (128x128 tiles, m97 structure), SWAPPED: A=w_qkv rows, B=tokens.
//   q: pre-scaled by 0.125*log2e, row-major [b,h,l,dh] (ushort4)
//   k: FRAGMENT-MAJOR K': ((bh*128 + jt)*2 + kc)*512 + lane*8 shorts
//   v: row-major [b,h,l,dh] -> repack_v makes V' + ext buffers
// ---------------------------------------------------------------------------
__global__ __launch_bounds__(256, 2) void gemm_qkv(
    const unsigned short* __restrict__ A, const unsigned short* __restrict__ Bm,
    unsigned short* __restrict__ qo, unsigned short* __restrict__ kp,
    unsigned short* __restrict__ vo)
{
  __shared__ __align__(16) unsigned short S[128 * 32 + 128 * 32];
  const int tid = threadIdx.x, wid = tid >> 6, lane = tid & 63;
  const int quad = lane >> 4, l15 = lane & 15;
  const int m0 = blockIdx.x * 128, n0 = blockIdx.y * 128;
  const int wm = (wid >> 1) * 64, wn = (wid & 1) * 64;

  f32x4 acc[4][4];
#pragma unroll
  for (int a = 0; a < 4; ++a)
#pragma unroll
    for (int b = 0; b < 4; ++b)
#pragma unroll
      for (int z = 0; z < 4; ++z) acc[a][b][z] = 0.f;

  for (int k0 = 0; k0 < ND; k0 += 32) {
#pragma unroll
    for (int p = 0; p < 4; ++p) {
      int c = p * 256 + wid * 64 + lane;
      if (c < 512) {
        int row = c >> 2, off = c & 3;
        gl_lds16(A + (size_t)(m0 + row) * ND + k0 + off * 8, &S[c * 8]);
      } else {
        int cb = c - 512;
        int row = cb >> 2, off = cb & 3;
        gl_lds16(Bm + (size_t)(n0 + row) * ND + k0 + off * 8, &S[c * 8]);
      }
    }
    __syncthreads();
    bf16x8 af[4], bfr[4];
#pragma unroll
    for (int mb = 0; mb < 4; ++mb)
      af[mb] = *(const bf16x8*)&S[(wm + mb * 16 + l15) * 32 + quad * 8];
#pragma unroll
    for (int nb = 0; nb < 4; ++nb)
      bfr[nb] = *(const bf16x8*)&S[4096 + (wn + nb * 16 + l15) * 32 + quad * 8];
#pragma unroll
    for (int mb = 0; mb < 4; ++mb)
#pragma unroll
      for (int nb = 0; nb < 4; ++nb)
        acc[mb][nb] = __builtin_amdgcn_mfma_f32_16x16x32_bf16(af[mb], bfr[nb], acc[mb][nb], 0, 0, 0);
    __syncthreads();
  }

  const float QSCALE = 0.125f * LOG2E;
#pragma unroll
  for (int mb = 0; mb < 4; ++mb) {
    int e0 = m0 + wm + mb * 16 + quad * 4;
    int s   = e0 >> 9;
    int hh  = (e0 >> 6) & 7;
    if (s == 1) {
      int kc  = mb >> 1;
      int q_t = ((mb & 1) << 1) + (quad >> 1);
      int par = quad & 1;
#pragma unroll
      for (int nb = 0; nb < 4; ++nb) {
        int token = n0 + wn + nb * 16 + l15;
        int bb = token >> 11, ll = token & 2047;
        int jt = ll >> 4;
        ushort4 o;
        o.x = f2bf(acc[mb][nb][0]);
        o.y = f2bf(acc[mb][nb][1]);
        o.z = f2bf(acc[mb][nb][2]);
        o.w = f2bf(acc[mb][nb][3]);
        size_t addr = (((size_t)(bb * NH + hh) * 128 + jt) * 2 + kc) * 512
                    + (q_t * 16 + l15) * 8 + par * 4;
        *(ushort4*)&kp[addr] = o;
      }
    } else {
      unsigned short* dst = (s == 0) ? qo : vo;
      float sc = (s == 0) ? QSCALE : 1.0f;
      int dh0 = e0 & 63;
#pragma unroll
      for (int nb = 0; nb < 4; ++nb) {
        int token = n0 + wn + nb * 16 + l15;
        int bb = token >> 11, ll = token & 2047;
        ushort4 o;
        o.x = f2bf(acc[mb][nb][0] * sc);
        o.y = f2bf(acc[mb][nb][1] * sc);
        o.z = f2bf(acc[mb][nb][2] * sc);
        o.w = f2bf(acc[mb][nb][3] * sc);
        *(ushort4*)&dst[(((size_t)bb * NH + hh) * NL + ll) * DH + dh0] = o;
      }
    }
  }
}

// ---------------------------------------------------------------------------
// repack_v + ext-bias builders. grid (NL/64, NB*NH), 256 thr.
//  (a) V row-major -> V' frag-major: ((bh*64+jc)*4+dht)*512 + lane*8
//  (b) k_ext frag-major: (bh*128 + jt)*512 + lane*8; lane=(quad,l15) holds
//      b_j[d=quad*8..+8] for j=jt*16+l15 (10 dims used, rest 0)
//  (c) q_ext row-major: (bh*NL + l)*32 + d  (10 dims used, rest 0)
// Bias bilinear decomposition (all values already in log2 units):
//  bias = sum_d a_i[d]*b_j[d], CI=log2e/(2 sigma_h^2), LGB=log2e*gb:
//   d0,1: a=ispf*split(riCm),      b=jspf          (riCm=-CI|pi|^2-LGB)
//   d2,3: a=ispf,                  b=jspf*split(rjC)  (rjC=-CI|pj|^2)
//   d4,5,6: a=ispf*(xh,xl,xh),     b=jspf*(Xh,Xh,Xl)  (x=pix, X=2CI*pjx)
//   d7,8,9: same for y
// ---------------------------------------------------------------------------
__global__ __launch_bounds__(256) void repack_v(
    const unsigned short* __restrict__ v, unsigned short* __restrict__ vp,
    const float* __restrict__ pospad, const float* __restrict__ log_sigma,
    const float* __restrict__ gbias_p, const int* __restrict__ ns_p,
    unsigned short* __restrict__ kext, unsigned short* __restrict__ qext)
{
  __shared__ unsigned short T[64][74];
  const int l0 = blockIdx.x * 64;
  const int bh = blockIdx.y;
  const int b  = bh >> 3, h = bh & 7;
  const int Ls = ns_p[0];
  const float gb  = gbias_p[0];
  const float sig = __expf(log_sigma[h]);
  const float CI  = LOG2E * 0.5f / (sig * sig);
  const float LGB = LOG2E * gb;
  const float* posb = pospad + (size_t)b * NL * 2;
  const int tid = threadIdx.x;

  // (a) V transpose/repack
  const unsigned short* src = v + ((size_t)bh * NL + l0) * DH;
  unsigned short* dst = vp + (size_t)bh * 131072 + (size_t)(l0 >> 5) * 2048;
#pragma unroll
  for (int p = 0; p < 2; ++p) {
    int c = p * 256 + tid;
    int row = c >> 3, seg = c & 7;
    *(uint4*)&T[row][seg * 8] = *(const uint4*)(src + row * DH + seg * 8);
  }
  __syncthreads();
#pragma unroll
  for (int p = 0; p < 2; ++p) {
    int c = p * 256 + tid;
    int l15 = c & 15, q = (c >> 4) & 3, dht = (c >> 6) & 3, jcl = c >> 8;
    unsigned short u[8];
#pragma unroll
    for (int t = 0; t < 8; ++t) u[t] = T[jcl * 32 + q * 8 + t][dht * 16 + l15];
    *(uint4*)(dst + (size_t)jcl * 2048 + dht * 512 + (q * 16 + l15) * 8) = *(uint4*)u;
  }

  // (b) k_ext: thread covers one lane-slot of one jt-chunk
  {
    int jtl  = tid >> 6;            // 0..3
    int lane = tid & 63;
    int quad = lane >> 4, l15 = lane & 15;
    int j = l0 + jtl * 16 + l15;
    unsigned short bv[16];
#pragma unroll
    for (int z = 0; z < 16; ++z) bv[z] = 0;
    if (j < Ls) {
      float2 p2 = *(const float2*)(posb + (size_t)j * 2);
      float rjC = -(CI * (p2.x * p2.x + p2.y * p2.y));
      unsigned short one = f2bf(1.0f);
      bv[0] = one; bv[1] = one;
      split2(rjC, bv[2], bv[3]);
      unsigned short Xh, Xl, Yh, Yl;
      split2(2.0f * CI * p2.x, Xh, Xl);
      split2(2.0f * CI * p2.y, Yh, Yl);
      bv[4] = Xh; bv[5] = Xh; bv[6] = Xl;
      bv[7] = Yh; bv[8] = Yh; bv[9] = Yl;
    }
    unsigned short o[8];
#pragma unroll
    for (int z = 0; z < 8; ++z) o[z] = bv[quad * 8 + z < 16 ? quad * 8 + z : 15];
    if (quad >= 2) {
#pragma unroll
      for (int z = 0; z < 8; ++z) o[z] = 0;
    }
    *(uint4*)(kext + ((size_t)bh * 128 + (l0 >> 4) + jtl) * 512 + lane * 8) = *(uint4*)o;
  }

  // (c) q_ext: thread covers 8 dims of one row
  {
    int row = tid >> 2, seg = tid & 3;
    int i = l0 + row;
    unsigned short av[16];
#pragma unroll
    for (int z = 0; z < 16; ++z) av[z] = 0;
    if (i < Ls) {
      float2 p2 = *(const float2*)(posb + (size_t)i * 2);
      float riCm = -(CI * (p2.x * p2.x + p2.y * p2.y)) - LGB;
      unsigned short one = f2bf(1.0f);
      split2(riCm, av[0], av[1]);
      av[2] = one; av[3] = one;
      unsigned short xh, xl, yh, yl;
      split2(p2.x, xh, xl);
      split2(p2.y, yh, yl);
      av[4] = xh; av[5] = xl; av[6] = xh;
      av[7] = yh; av[8] = yl; av[9] = yh;
    }
    unsigned short o[8];
#pragma unroll
    for (int z = 0; z < 8; ++z) o[z] = (seg * 8 + z < 16) ? av[seg * 8 + z] : 0;
    if (seg >= 2) {
#pragma unroll
      for (int z = 0; z < 8; ++z) o[z] = 0;
    }
    *(uint4*)(qext + ((size_t)bh * NL + i) * 32 + seg * 8) = *(uint4*)o;
  }
}

// ---------------------------------------------------------------------------
// Flash attention R9: S^T orientation (R4-verified operand convention),
// barrier-free, frag-direct K'/K_ext/V' loads, bias folded into a 3rd MFMA.
// softmax body = add + exp2 + add + pack. P: b64 stores / b128 loads,
// wave-private LDS. Split-j=JS partials (bf16 accO + f32 rsum).
// ---------------------------------------------------------------------------
__global__ __launch_bounds__(256, 2) void flash_kernel(
    const unsigned short* __restrict__ qb, const unsigned short* __restrict__ qeb,
    const unsigned short* __restrict__ kp, const unsigned short* __restrict__ keb,
    const unsigned short* __restrict__ vp, const float* __restrict__ gbias_p,
    unsigned short* __restrict__ Pb, float* __restrict__ rsbuf)
{
  const int it = blockIdx.x >> 2;       // 0..15
  const int js = blockIdx.x & 3;        // 0..3
  const int h  = blockIdx.y;
  const int b  = blockIdx.z;
  const int i0 = it * 128;
  const int jbase = js * (NL / JS);     // 512 j per block
  const float CBL = -8.0f * LOG2E + LOG2E * gbias_p[0];

  const int tid  = threadIdx.x;
  const int wid  = tid >> 6;      // 0..3
  const int lane = tid & 63;
  const int quad = lane >> 4;
  const int l15  = lane & 15;

  __shared__ __align__(16) unsigned short Ps[128][78];   // wave-private rows

  const size_t bh = (size_t)b * NH + h;
  const unsigned short* qbase  = qb  + (bh * NL + i0 + wid * 32) * DH;
  const unsigned short* qebase = qeb + (bh * NL + i0 + wid * 32) * 32;
  const unsigned short* kpb    = kp  + bh * 131072;
  const unsigned short* kebb   = keb + bh * 65536;
  const unsigned short* vpb    = vp  + bh * 131072;

  // Q B-frags (lane l15 = i) + ext
  bf16x8 qf[2][2], qfe[2];
#pragma unroll
  for (int ib = 0; ib < 2; ++ib) {
#pragma unroll
    for (int kc = 0; kc < 2; ++kc)
      qf[ib][kc] = *(const bf16x8*)(qbase + (size_t)(ib * 16 + l15) * DH + kc * 32 + quad * 8);
    qfe[ib] = *(const bf16x8*)(qebase + (size_t)(ib * 16 + l15) * 32 + quad * 8);
  }

  f32x4 accO[4][2];   // [dht][ib]; C row = dh, col = i
  float rsum[2];
#pragma unroll
  for (int d = 0; d < 4; ++d)
#pragma unroll
    for (int ib = 0; ib < 2; ++ib)
#pragma unroll
      for (int z = 0; z < 4; ++z) accO[d][ib][z] = 0.f;
  rsum[0] = 0.f; rsum[1] = 0.f;

  for (int jt = 0; jt < NL / JS / 64; ++jt) {
    const int j0 = jbase + jt * 64;
    const int jt0 = j0 >> 4;

    // V' B/A-frags (lane l15 = dh row, quad = j chunk) — issue early
    bf16x8 vf[4][2];
#pragma unroll
    for (int dht = 0; dht < 4; ++dht)
#pragma unroll
      for (int jc = 0; jc < 2; ++jc)
        vf[dht][jc] = *(const bf16x8*)(vpb + ((size_t)((j0 >> 5) + jc) * 4 + dht) * 512 + lane * 8);

    // per j-block: S^T = K Q^T (+ bias via ext dims), softmax, b64 P store
#pragma unroll
    for (int jb = 0; jb < 4; ++jb) {
      bf16x8 kf0 = *(const bf16x8*)(kpb + ((size_t)(jt0 + jb) * 2 + 0) * 512 + lane * 8);
      bf16x8 kf1 = *(const bf16x8*)(kpb + ((size_t)(jt0 + jb) * 2 + 1) * 512 + lane * 8);
      bf16x8 kfe = *(const bf16x8*)(kebb + (size_t)(jt0 + jb) * 512 + lane * 8);
#pragma unroll
      for (int ib = 0; ib < 2; ++ib) {
        f32x4 accS;
#pragma unroll
        for (int z = 0; z < 4; ++z) accS[z] = 0.f;
        accS = __builtin_amdgcn_mfma_f32_16x16x32_bf16(kf0, qf[ib][0], accS, 0, 0, 0);
        accS = __builtin_amdgcn_mfma_f32_16x16x32_bf16(kf1, qf[ib][1], accS, 0, 0, 0);
        accS = __builtin_amdgcn_mfma_f32_16x16x32_bf16(kfe, qfe[ib], accS, 0, 0, 0);
        float p0 = fexp2(accS[0] + CBL);
        float p1 = fexp2(accS[1] + CBL);
        float p2 = fexp2(accS[2] + CBL);
        float p3 = fexp2(accS[3] + CBL);
        rsum[ib] += (p0 + p1) + (p2 + p3);
        uint2 w;
        w.x = (uint32_t)f2bf(p0) | ((uint32_t)f2bf(p1) << 16);
        w.y = (uint32_t)f2bf(p2) | ((uint32_t)f2bf(p3) << 16);
        *(uint2*)&Ps[wid * 32 + ib * 16 + l15][jb * 16 + quad * 4] = w;
      }
    }

    // O^T += V^T P^T (wave-private Ps rows; same-wave lgkm ordering)
    bf16x8 pf[2][2];
#pragma unroll
    for (int ib = 0; ib < 2; ++ib)
#pragma unroll
      for (int jc = 0; jc < 2; ++jc)
        pf[ib][jc] = *(const bf16x8*)&Ps[wid * 32 + ib * 16 + l15][jc * 32 + quad * 8];
#pragma unroll
    for (int dht = 0; dht < 4; ++dht)
#pragma unroll
      for (int ib = 0; ib < 2; ++ib) {
        accO[dht][ib] = __builtin_amdgcn_mfma_f32_16x16x32_bf16(vf[dht][0], pf[ib][0], accO[dht][ib], 0, 0, 0);
        accO[dht][ib] = __builtin_amdgcn_mfma_f32_16x16x32_bf16(vf[dht][1], pf[ib][1], accO[dht][ib], 0, 0, 0);
      }
  }

  // ---- epilogue: unnormalized partials (bf16 accO, f32 rsum) ----
  const size_t rgbase = bh * NL + i0;
  const size_t poff = (size_t)js * RG_TOT * DH;
#pragma unroll
  for (int ib = 0; ib < 2; ++ib) {
    float v = rsum[ib];
    v += __shfl_xor(v, 16);
    v += __shfl_xor(v, 32);
    int irow = wid * 32 + ib * 16 + l15;
    if (quad == 0)
      rsbuf[(size_t)js * RG_TOT + rgbase + irow] = v;
#pragma unroll
    for (int dht = 0; dht < 4; ++dht) {
      ushort4 o;
      o.x = f2bf(accO[dht][ib][0]);
      o.y = f2bf(accO[dht][ib][1]);
      o.z = f2bf(accO[dht][ib][2]);
      o.w = f2bf(accO[dht][ib][3]);
      *(ushort4*)&Pb[poff + (rgbase + irow) * DH + dht * 16 + quad * 4] = o;
    }
  }
}

// ---------------------------------------------------------------------------
// Output GEMM with FUSED combine: A=w_out (gl_lds16), B=attn reconstructed
// from split-j partials during staging. 64x128 tiles, 256 blocks.
// ---------------------------------------------------------------------------
__global__ __launch_bounds__(256, 2) void gemm_out(
    const unsigned short* __restrict__ A, const unsigned short* __restrict__ Pb,
    const float* __restrict__ rsbuf, const float* __restrict__ bias,
    float* __restrict__ out)
{
  __shared__ __align__(16) unsigned short S[64 * 32 + 128 * 32];  // A | B
  const int tid = threadIdx.x, wid = tid >> 6, lane = tid & 63;
  const int quad = lane >> 4, l15 = lane & 15;
  const int m0 = blockIdx.x * 64, n0 = blockIdx.y * 128;
  const int wm = (wid >> 1) * 32, wn = (wid & 1) * 64;

  f32x4 acc[2][4];
#pragma unroll
  for (int a = 0; a < 2; ++a)
#pragma unroll
    for (int b = 0; b < 4; ++b)
#pragma unroll
      for (int z = 0; z < 4; ++z) acc[a][b][z] = 0.f;

  for (int k0 = 0; k0 < ND; k0 += 32) {
    // A tile: 256 chunks via async DMA
    {
      int c = wid * 64 + lane;
      int row = c >> 2, off = c & 3;
      gl_lds16(A + (size_t)(m0 + row) * ND + k0 + off * 8, &S[c * 8]);
    }
    // B tile: combine 4 partial slices + normalize, 512 chunks
    int head = k0 >> 6;
    int dhb  = k0 & 32;
#pragma unroll
    for (int p = 0; p < 2; ++p) {
      int cb = p * 256 + tid;
      int row = cb >> 2, off = cb & 3;
      int token = n0 + row;
      int bb = token >> 11, ll = token & 2047;
      size_t rg = ((size_t)(bb * NH + head)) * NL + ll;
      float rs = rsbuf[rg] + rsbuf[RG_TOT + rg] + rsbuf[2 * RG_TOT + rg] + rsbuf[3 * RG_TOT + rg];
      float rinv = 1.0f / rs;
      float s[8];
#pragma unroll
      for (int z = 0; z < 8; ++z) s[z] = 0.f;
#pragma unroll
      for (int jp = 0; jp < JS; ++jp) {
        ushort4 u0 = *(const ushort4*)&Pb[((size_t)jp * RG_TOT + rg) * DH + dhb + off * 8];
        ushort4 u1 = *(const ushort4*)&Pb[((size_t)jp * RG_TOT + rg) * DH + dhb + off * 8 + 4];
        s[0] += bf2f(u0.x); s[1] += bf2f(u0.y); s[2] += bf2f(u0.z); s[3] += bf2f(u0.w);
        s[4] += bf2f(u1.x); s[5] += bf2f(u1.y); s[6] += bf2f(u1.z); s[7] += bf2f(u1.w);
      }
      uint32_t w0 = (uint32_t)f2bf(s[0] * rinv) | ((uint32_t)f2bf(s[1] * rinv) << 16);
      uint32_t w1 = (uint32_t)f2bf(s[2] * rinv) | ((uint32_t)f2bf(s[3] * rinv) << 16);
      uint32_t w2 = (uint32_t)f2bf(s[4] * rinv) | ((uint32_t)f2bf(s[5] * rinv) << 16);
      uint32_t w3 = (uint32_t)f2bf(s[6] * rinv) | ((uint32_t)f2bf(s[7] * rinv) << 16);
      *(uint4*)&S[2048 + cb * 8] = make_uint4(w0, w1, w2, w3);
    }
    __syncthreads();
    bf16x8 af[2], bfr[4];
#pragma unroll
    for (int mb = 0; mb < 2; ++mb)
      af[mb] = *(const bf16x8*)&S[(wm + mb * 16 + l15) * 32 + quad * 8];
#pragma unroll
    for (int nb = 0; nb < 4; ++nb)
      bfr[nb] = *(const bf16x8*)&S[2048 + (wn + nb * 16 + l15) * 32 + quad * 8];
#pragma unroll
    for (int mb = 0; mb < 2; ++mb)
#pragma unroll
      for (int nb = 0; nb < 4; ++nb)
        acc[mb][nb] = __builtin_amdgcn_mfma_f32_16x16x32_bf16(af[mb], bfr[nb], acc[mb][nb], 0, 0, 0);
    __syncthreads();
  }

#pragma unroll
  for (int mb = 0; mb < 2; ++mb) {
    int e0 = m0 + wm + mb * 16 + quad * 4;
    float4 bv = *(const float4*)&bias[e0];
#pragma unroll
    for (int nb = 0; nb < 4; ++nb) {
      int token = n0 + wn + nb * 16 + l15;
      float4 o;
      o.x = acc[mb][nb][0] + bv.x;
      o.y = acc[mb][nb][1] + bv.y;
      o.z = acc[mb][nb][2] + bv.z;
      o.w = acc[mb][nb][3] + bv.w;
      *(float4*)&out[(size_t)token * ND + e0] = o;
    }
  }
}

// ---------------------------------------------------------------------------
extern "C" void kernel_launch(void* const* d_in, const int* in_sizes, int n_in,
                              void* d_out, int out_size, void* d_ws, size_t ws_size,
                              hipStream_t stream) {
  const float* x         = (const float*)d_in[0];
  const float* positions = (const float*)d_in[1];
  const float* w_qkv     = (const float*)d_in[2];
  const float* w_out     = (const float*)d_in[3];
  const float* b_out     = (const float*)d_in[4];
  const float* log_sigma = (const float*)d_in[5];
  const float* gbias     = (const float*)d_in[6];
  const int*   ns        = (const int*)d_in[7];

  // workspace layout (shorts unless noted); lifetime overlap:
  //   region R: [wqb] (dead after gemm_qkv) overlapped by [Pb | rsbuf]
  unsigned short* ws   = (unsigned short*)d_ws;
  unsigned short* xb   = ws;                   // 2,097,152
  unsigned short* wob  = xb   + 2097152;       //   262,144
  unsigned short* qbf  = wob  + 262144;        // 2,097,152
  unsigned short* kpf  = qbf  + 2097152;       // 2,097,152 (K' frag-major)
  unsigned short* vbf  = kpf  + 2097152;       // 2,097,152 (v row-major)
  unsigned short* vpf  = vbf  + 2097152;       // 2,097,152 (V' frag-major)
  unsigned short* qext = vpf  + 2097152;       // 1,048,576
  unsigned short* kext = qext + 1048576;       // 1,048,576
  float* pospad = (float*)(kext + 1048576);    // NB*2048*2 f32
  unsigned short* R    = (unsigned short*)(pospad + NB * NL * 2);
  unsigned short* wqb  = R;                    //   786,432
  unsigned short* Pb   = R;                    // JS*32768*64 bf16 = 16.8 MB
  float* rsbuf = (float*)(Pb + (size_t)JS * RG_TOT * DH);  // JS*32768 f32

  // 1) f32 -> bf16 + zero-padded positions
  cvt_f32_bf16<<<(TOTC + NB * 1024 + 255) / 256, 256, 0, stream>>>(
      x, w_qkv, w_out, positions, ns, xb, wqb, wob, pospad);

  // 2) QKV projection -> q(scaled) row-major, K' frag-major, v row-major
  dim3 g1((3 * NH * DH) / 128, NB * NL / 128);
  gemm_qkv<<<g1, 256, 0, stream>>>(wqb, xb, qbf, kpf, vbf);

  // 3) V' repack + bias-ext builders (k_ext, q_ext)
  dim3 gr(NL / 64, NB * NH);
  repack_v<<<gr, 256, 0, stream>>>(vbf, vpf, pospad, log_sigma, gbias, ns, kext, qext);

  // 4) flash attention partials (split-j=4, barrier-free, ext-bias MFMA)
  dim3 g2((NL / 128) * JS, NH, NB);
  flash_kernel<<<g2, 256, 0, stream>>>(qbf, qext, kpf, kext, vpf, gbias, Pb, rsbuf);

  // 5) output projection with fused combine + bias -> f32 d_out
  dim3 g3(ND / 64, NB * NL / 128);
  gemm_out<<<g3, 256, 0, stream>>>(wob, Pb, rsbuf, b_out, (float*)d_out);
}

// Round 10
// 152.768 us; speedup vs baseline: 1.0929x; 1.0929x over previous
//
#include <hip/hip_runtime.h>
#include <stdint.h>
#include <stddef.h>

// Problem constants (fixed by setup_inputs)
#define NB   2      // batch
#define NL   2048   // seq len
#define ND   512    // model dim
#define NH   8      // heads
#define DH   64     // dim head
#define LOG2E 1.44269504f
#define RG_TOT 32768  // NB*NH*NL rows of partials
#define JS   4      // split-j factor

typedef __attribute__((ext_vector_type(8))) short bf16x8;
typedef __attribute__((ext_vector_type(4))) float f32x4;

__device__ __forceinline__ unsigned short f2bf(float f) {
  union { float f; unsigned int u; } c; c.f = f;
  unsigned int u = c.u;
  unsigned int r = u + 0x7fffu + ((u >> 16) & 1u);
  return (unsigned short)(r >> 16);
}

__device__ __forceinline__ float bf2f(unsigned short u) {
  union { unsigned int i; float f; } c; c.i = ((unsigned int)u) << 16; return c.f;
}

// hi/lo bf16 split: hi+lo == v to ~2^-16 relative
__device__ __forceinline__ void split2(float v, unsigned short& h, unsigned short& l) {
  h = f2bf(v);
  l = f2bf(v - bf2f(h));
}

__device__ __forceinline__ float fexp2(float x) {
#if __has_builtin(__builtin_amdgcn_exp2f)
  return __builtin_amdgcn_exp2f(x);
#else
  return exp2f(x);
#endif
}

// async global->LDS 16B copy; lanes of a wave must target base + lane*16
__device__ __forceinline__ void gl_lds16(const unsigned short* g, unsigned short* l) {
#if __has_builtin(__builtin_amdgcn_global_load_lds)
  __builtin_amdgcn_global_load_lds(
      (const __attribute__((address_space(1))) unsigned int*)g,
      (__attribute__((address_space(3))) unsigned int*)l, 16, 0, 0);
#else
  *(uint4*)l = *(const uint4*)g;
#endif
}

// ---------------------------------------------------------------------------
// f32 -> bf16 conversion for x, w_qkv, w_out + zero-padded positions buffer
// ---------------------------------------------------------------------------
#define XC  524288   // 4096*512/4
#define WQC 196608   // 1536*512/4
#define WOC 65536    // 512*512/4
#define TOTC (XC + WQC + WOC)
__global__ void cvt_f32_bf16(const float* __restrict__ x, const float* __restrict__ wq,
                             const float* __restrict__ wo, const float* __restrict__ positions,
                             const int* __restrict__ ns_p,
                             unsigned short* __restrict__ xb, unsigned short* __restrict__ wqb,
                             unsigned short* __restrict__ wob, float* __restrict__ pospad) {
  int idx = blockIdx.x * 256 + threadIdx.x;
  if (idx < TOTC) {
    const float* src; unsigned short* dst; int off;
    if (idx < XC)            { src = x;  dst = xb;  off = idx; }
    else if (idx < XC + WQC) { src = wq; dst = wqb; off = idx - XC; }
    else                     { src = wo; dst = wob; off = idx - XC - WQC; }
    float4 f = ((const float4*)src)[off];
    ushort4 o;
    o.x = f2bf(f.x); o.y = f2bf(f.y); o.z = f2bf(f.z); o.w = f2bf(f.w);
    ((ushort4*)dst)[off] = o;
  } else {
    int i2 = idx - TOTC;
    if (i2 < NB * 1024) {
      int b = i2 >> 10;
      int jj = (i2 & 1023) * 2;
      int Ls = ns_p[0];
      float4 o = make_float4(0.f, 0.f, 0.f, 0.f);
      if (jj < Ls) { o.x = positions[((size_t)b * Ls + jj) * 2];
                     o.y = positions[((size_t)b * Ls + jj) * 2 + 1]; }
      if (jj + 1 < Ls) { o.z = positions[((size_t)b * Ls + jj + 1) * 2];
                         o.w = positions[((size_t)b * Ls + jj + 1) * 2 + 1]; }
      *(float4*)&pospad[((size_t)b * NL + jj) * 2] = o;
    }
  }
}

// ---------------------------------------------------------------------------
// QKV GEMM (128x128 tiles, m97 structure), SWAPPED: A=w_qkv rows, B=tokens.
//   q: pre-scaled by 0.125*log2e, row-major [b,h,l,dh] (ushort4)
//   k: FRAGMENT-MAJOR K': ((bh*128 + jt)*2 + kc)*512 + lane*8 shorts
//   v: row-major [b,h,l,dh] -> repack_v makes V' + ext buffers
// ---------------------------------------------------------------------------
__global__ __launch_bounds__(256, 2) void gemm_qkv(
    const unsigned short* __restrict__ A, const unsigned short* __restrict__ Bm,
    unsigned short* __restrict__ qo, unsigned short* __restrict__ kp,
    unsigned short* __restrict__ vo)
{
  __shared__ __align__(16) unsigned short S[128 * 32 + 128 * 32];
  const int tid = threadIdx.x, wid = tid >> 6, lane = tid & 63;
  const int quad = lane >> 4, l15 = lane & 15;
  const int m0 = blockIdx.x * 128, n0 = blockIdx.y * 128;
  const int wm = (wid >> 1) * 64, wn = (wid & 1) * 64;

  f32x4 acc[4][4];
#pragma unroll
  for (int a = 0; a < 4; ++a)
#pragma unroll
    for (int b = 0; b < 4; ++b)
#pragma unroll
      for (int z = 0; z < 4; ++z) acc[a][b][z] = 0.f;

  for (int k0 = 0; k0 < ND; k0 += 32) {
#pragma unroll
    for (int p = 0; p < 4; ++p) {
      int c = p * 256 + wid * 64 + lane;
      if (c < 512) {
        int row = c >> 2, off = c & 3;
        gl_lds16(A + (size_t)(m0 + row) * ND + k0 + off * 8, &S[c * 8]);
      } else {
        int cb = c - 512;
        int row = cb >> 2, off = cb & 3;
        gl_lds16(Bm + (size_t)(n0 + row) * ND + k0 + off * 8, &S[c * 8]);
      }
    }
    __syncthreads();
    bf16x8 af[4], bfr[4];
#pragma unroll
    for (int mb = 0; mb < 4; ++mb)
      af[mb] = *(const bf16x8*)&S[(wm + mb * 16 + l15) * 32 + quad * 8];
#pragma unroll
    for (int nb = 0; nb < 4; ++nb)
      bfr[nb] = *(const bf16x8*)&S[4096 + (wn + nb * 16 + l15) * 32 + quad * 8];
#pragma unroll
    for (int mb = 0; mb < 4; ++mb)
#pragma unroll
      for (int nb = 0; nb < 4; ++nb)
        acc[mb][nb] = __builtin_amdgcn_mfma_f32_16x16x32_bf16(af[mb], bfr[nb], acc[mb][nb], 0, 0, 0);
    __syncthreads();
  }

  const float QSCALE = 0.125f * LOG2E;
#pragma unroll
  for (int mb = 0; mb < 4; ++mb) {
    int e0 = m0 + wm + mb * 16 + quad * 4;
    int s   = e0 >> 9;
    int hh  = (e0 >> 6) & 7;
    if (s == 1) {
      int kc  = mb >> 1;
      int q_t = ((mb & 1) << 1) + (quad >> 1);
      int par = quad & 1;
#pragma unroll
      for (int nb = 0; nb < 4; ++nb) {
        int token = n0 + wn + nb * 16 + l15;
        int bb = token >> 11, ll = token & 2047;
        int jt = ll >> 4;
        ushort4 o;
        o.x = f2bf(acc[mb][nb][0]);
        o.y = f2bf(acc[mb][nb][1]);
        o.z = f2bf(acc[mb][nb][2]);
        o.w = f2bf(acc[mb][nb][3]);
        size_t addr = (((size_t)(bb * NH + hh) * 128 + jt) * 2 + kc) * 512
                    + (q_t * 16 + l15) * 8 + par * 4;
        *(ushort4*)&kp[addr] = o;
      }
    } else {
      unsigned short* dst = (s == 0) ? qo : vo;
      float sc = (s == 0) ? QSCALE : 1.0f;
      int dh0 = e0 & 63;
#pragma unroll
      for (int nb = 0; nb < 4; ++nb) {
        int token = n0 + wn + nb * 16 + l15;
        int bb = token >> 11, ll = token & 2047;
        ushort4 o;
        o.x = f2bf(acc[mb][nb][0] * sc);
        o.y = f2bf(acc[mb][nb][1] * sc);
        o.z = f2bf(acc[mb][nb][2] * sc);
        o.w = f2bf(acc[mb][nb][3] * sc);
        *(ushort4*)&dst[(((size_t)bb * NH + hh) * NL + ll) * DH + dh0] = o;
      }
    }
  }
}

// ---------------------------------------------------------------------------
// repack_v + ext-bias builders. grid (NL/64, NB*NH), 256 thr.
//  (a) V row-major -> V' frag-major: ((bh*64+jc)*4+dht)*512 + lane*8
//  (b) k_ext frag-major: (bh*128 + jt)*512 + lane*8 (10 bias dims, rest 0)
//  (c) q_ext row-major: (bh*NL + l)*32 + d  (10 bias dims, rest 0)
// Bias bilinear decomposition (log2 units), CI=log2e/(2 sig^2), LGB=log2e*gb:
//   d0,1: a=split(riCm)      b=jspf          (riCm=-CI|pi|^2-LGB, masked i)
//   d2,3: a=ispf             b=split(rjC)    (rjC=-CI|pj|^2, masked j)
//   d4,5,6: a=(xh,xl,xh)     b=(Xh,Xh,Xl)    (x=pix, X=2CI*pjx)
//   d7,8,9: same for y
// ---------------------------------------------------------------------------
__global__ __launch_bounds__(256) void repack_v(
    const unsigned short* __restrict__ v, unsigned short* __restrict__ vp,
    const float* __restrict__ pospad, const float* __restrict__ log_sigma,
    const float* __restrict__ gbias_p, const int* __restrict__ ns_p,
    unsigned short* __restrict__ kext, unsigned short* __restrict__ qext)
{
  __shared__ unsigned short T[64][74];
  const int l0 = blockIdx.x * 64;
  const int bh = blockIdx.y;
  const int b  = bh >> 3, h = bh & 7;
  const int Ls = ns_p[0];
  const float gb  = gbias_p[0];
  const float sig = __expf(log_sigma[h]);
  const float CI  = LOG2E * 0.5f / (sig * sig);
  const float LGB = LOG2E * gb;
  const float* posb = pospad + (size_t)b * NL * 2;
  const int tid = threadIdx.x;

  // (a) V transpose/repack
  const unsigned short* src = v + ((size_t)bh * NL + l0) * DH;
  unsigned short* dst = vp + (size_t)bh * 131072 + (size_t)(l0 >> 5) * 2048;
#pragma unroll
  for (int p = 0; p < 2; ++p) {
    int c = p * 256 + tid;
    int row = c >> 3, seg = c & 7;
    *(uint4*)&T[row][seg * 8] = *(const uint4*)(src + row * DH + seg * 8);
  }
  __syncthreads();
#pragma unroll
  for (int p = 0; p < 2; ++p) {
    int c = p * 256 + tid;
    int l15 = c & 15, q = (c >> 4) & 3, dht = (c >> 6) & 3, jcl = c >> 8;
    unsigned short u[8];
#pragma unroll
    for (int t = 0; t < 8; ++t) u[t] = T[jcl * 32 + q * 8 + t][dht * 16 + l15];
    *(uint4*)(dst + (size_t)jcl * 2048 + dht * 512 + (q * 16 + l15) * 8) = *(uint4*)u;
  }

  // (b) k_ext: thread covers one lane-slot of one jt-chunk
  {
    int jtl  = tid >> 6;            // 0..3
    int lane = tid & 63;
    int quad = lane >> 4, l15 = lane & 15;
    int j = l0 + jtl * 16 + l15;
    unsigned short bv[16];
#pragma unroll
    for (int z = 0; z < 16; ++z) bv[z] = 0;
    if (j < Ls) {
      float2 p2 = *(const float2*)(posb + (size_t)j * 2);
      float rjC = -(CI * (p2.x * p2.x + p2.y * p2.y));
      unsigned short one = f2bf(1.0f);
      bv[0] = one; bv[1] = one;
      split2(rjC, bv[2], bv[3]);
      unsigned short Xh, Xl, Yh, Yl;
      split2(2.0f * CI * p2.x, Xh, Xl);
      split2(2.0f * CI * p2.y, Yh, Yl);
      bv[4] = Xh; bv[5] = Xh; bv[6] = Xl;
      bv[7] = Yh; bv[8] = Yh; bv[9] = Yl;
    }
    unsigned short o[8];
#pragma unroll
    for (int z = 0; z < 8; ++z) o[z] = bv[quad * 8 + z < 16 ? quad * 8 + z : 15];
    if (quad >= 2) {
#pragma unroll
      for (int z = 0; z < 8; ++z) o[z] = 0;
    }
    *(uint4*)(kext + ((size_t)bh * 128 + (l0 >> 4) + jtl) * 512 + lane * 8) = *(uint4*)o;
  }

  // (c) q_ext: thread covers 8 dims of one row
  {
    int row = tid >> 2, seg = tid & 3;
    int i = l0 + row;
    unsigned short av[16];
#pragma unroll
    for (int z = 0; z < 16; ++z) av[z] = 0;
    if (i < Ls) {
      float2 p2 = *(const float2*)(posb + (size_t)i * 2);
      float riCm = -(CI * (p2.x * p2.x + p2.y * p2.y)) - LGB;
      unsigned short one = f2bf(1.0f);
      split2(riCm, av[0], av[1]);
      av[2] = one; av[3] = one;
      unsigned short xh, xl, yh, yl;
      split2(p2.x, xh, xl);
      split2(p2.y, yh, yl);
      av[4] = xh; av[5] = xl; av[6] = xh;
      av[7] = yh; av[8] = yl; av[9] = yh;
    }
    unsigned short o[8];
#pragma unroll
    for (int z = 0; z < 8; ++z) o[z] = (seg * 8 + z < 16) ? av[seg * 8 + z] : 0;
    if (seg >= 2) {
#pragma unroll
      for (int z = 0; z < 8; ++z) o[z] = 0;
    }
    *(uint4*)(qext + ((size_t)bh * NL + i) * 32 + seg * 8) = *(uint4*)o;
  }
}

// ---------------------------------------------------------------------------
// Flash attention (R9-verified): S^T orientation, barrier-free, frag-direct
// K'/K_ext/V' loads, bias folded into a 3rd MFMA. softmax body = add + exp2 +
// add + pack. P: b64 stores / b128 loads, wave-private LDS. Split-j=JS
// partials (bf16 accO + f32 rsum).
// ---------------------------------------------------------------------------
__global__ __launch_bounds__(256, 2) void flash_kernel(
    const unsigned short* __restrict__ qb, const unsigned short* __restrict__ qeb,
    const unsigned short* __restrict__ kp, const unsigned short* __restrict__ keb,
    const unsigned short* __restrict__ vp, const float* __restrict__ gbias_p,
    unsigned short* __restrict__ Pb, float* __restrict__ rsbuf)
{
  const int it = blockIdx.x >> 2;       // 0..15
  const int js = blockIdx.x & 3;        // 0..3
  const int h  = blockIdx.y;
  const int b  = blockIdx.z;
  const int i0 = it * 128;
  const int jbase = js * (NL / JS);     // 512 j per block
  const float CBL = -8.0f * LOG2E + LOG2E * gbias_p[0];

  const int tid  = threadIdx.x;
  const int wid  = tid >> 6;      // 0..3
  const int lane = tid & 63;
  const int quad = lane >> 4;
  const int l15  = lane & 15;

  __shared__ __align__(16) unsigned short Ps[128][78];   // wave-private rows

  const size_t bh = (size_t)b * NH + h;
  const unsigned short* qbase  = qb  + (bh * NL + i0 + wid * 32) * DH;
  const unsigned short* qebase = qeb + (bh * NL + i0 + wid * 32) * 32;
  const unsigned short* kpb    = kp  + bh * 131072;
  const unsigned short* kebb   = keb + bh * 65536;
  const unsigned short* vpb    = vp  + bh * 131072;

  // Q B-frags (lane l15 = i) + ext
  bf16x8 qf[2][2], qfe[2];
#pragma unroll
  for (int ib = 0; ib < 2; ++ib) {
#pragma unroll
    for (int kc = 0; kc < 2; ++kc)
      qf[ib][kc] = *(const bf16x8*)(qbase + (size_t)(ib * 16 + l15) * DH + kc * 32 + quad * 8);
    qfe[ib] = *(const bf16x8*)(qebase + (size_t)(ib * 16 + l15) * 32 + quad * 8);
  }

  f32x4 accO[4][2];   // [dht][ib]; C row = dh, col = i
  float rsum[2];
#pragma unroll
  for (int d = 0; d < 4; ++d)
#pragma unroll
    for (int ib = 0; ib < 2; ++ib)
#pragma unroll
      for (int z = 0; z < 4; ++z) accO[d][ib][z] = 0.f;
  rsum[0] = 0.f; rsum[1] = 0.f;

  for (int jt = 0; jt < NL / JS / 64; ++jt) {
    const int j0 = jbase + jt * 64;
    const int jt0 = j0 >> 4;

    // V' frags (lane = dh-major) — issue early, consumed after softmax
    bf16x8 vf[4][2];
#pragma unroll
    for (int dht = 0; dht < 4; ++dht)
#pragma unroll
      for (int jc = 0; jc < 2; ++jc)
        vf[dht][jc] = *(const bf16x8*)(vpb + ((size_t)((j0 >> 5) + jc) * 4 + dht) * 512 + lane * 8);

    // per j-block: S^T = K Q^T (+ bias via ext dims), softmax, b64 P store
#pragma unroll
    for (int jb = 0; jb < 4; ++jb) {
      bf16x8 kf0 = *(const bf16x8*)(kpb + ((size_t)(jt0 + jb) * 2 + 0) * 512 + lane * 8);
      bf16x8 kf1 = *(const bf16x8*)(kpb + ((size_t)(jt0 + jb) * 2 + 1) * 512 + lane * 8);
      bf16x8 kfe = *(const bf16x8*)(kebb + (size_t)(jt0 + jb) * 512 + lane * 8);
#pragma unroll
      for (int ib = 0; ib < 2; ++ib) {
        f32x4 accS;
#pragma unroll
        for (int z = 0; z < 4; ++z) accS[z] = 0.f;
        accS = __builtin_amdgcn_mfma_f32_16x16x32_bf16(kf0, qf[ib][0], accS, 0, 0, 0);
        accS = __builtin_amdgcn_mfma_f32_16x16x32_bf16(kf1, qf[ib][1], accS, 0, 0, 0);
        accS = __builtin_amdgcn_mfma_f32_16x16x32_bf16(kfe, qfe[ib], accS, 0, 0, 0);
        float p0 = fexp2(accS[0] + CBL);
        float p1 = fexp2(accS[1] + CBL);
        float p2 = fexp2(accS[2] + CBL);
        float p3 = fexp2(accS[3] + CBL);
        rsum[ib] += (p0 + p1) + (p2 + p3);
        uint2 w;
        w.x = (uint32_t)f2bf(p0) | ((uint32_t)f2bf(p1) << 16);
        w.y = (uint32_t)f2bf(p2) | ((uint32_t)f2bf(p3) << 16);
        *(uint2*)&Ps[wid * 32 + ib * 16 + l15][jb * 16 + quad * 4] = w;
      }
    }

    // O^T += V^T P^T (wave-private Ps rows; same-wave lgkm ordering)
    bf16x8 pf[2][2];
#pragma unroll
    for (int ib = 0; ib < 2; ++ib)
#pragma unroll
      for (int jc = 0; jc < 2; ++jc)
        pf[ib][jc] = *(const bf16x8*)&Ps[wid * 32 + ib * 16 + l15][jc * 32 + quad * 8];
#pragma unroll
    for (int dht = 0; dht < 4; ++dht)
#pragma unroll
      for (int ib = 0; ib < 2; ++ib) {
        accO[dht][ib] = __builtin_amdgcn_mfma_f32_16x16x32_bf16(vf[dht][0], pf[ib][0], accO[dht][ib], 0, 0, 0);
        accO[dht][ib] = __builtin_amdgcn_mfma_f32_16x16x32_bf16(vf[dht][1], pf[ib][1], accO[dht][ib], 0, 0, 0);
      }
  }

  // ---- epilogue: unnormalized partials (bf16 accO, f32 rsum) ----
  const size_t rgbase = bh * NL + i0;
  const size_t poff = (size_t)js * RG_TOT * DH;
#pragma unroll
  for (int ib = 0; ib < 2; ++ib) {
    float v = rsum[ib];
    v += __shfl_xor(v, 16);
    v += __shfl_xor(v, 32);
    int irow = wid * 32 + ib * 16 + l15;
    if (quad == 0)
      rsbuf[(size_t)js * RG_TOT + rgbase + irow] = v;
#pragma unroll
    for (int dht = 0; dht < 4; ++dht) {
      ushort4 o;
      o.x = f2bf(accO[dht][ib][0]);
      o.y = f2bf(accO[dht][ib][1]);
      o.z = f2bf(accO[dht][ib][2]);
      o.w = f2bf(accO[dht][ib][3]);
      *(ushort4*)&Pb[poff + (rgbase + irow) * DH + dht * 16 + quad * 4] = o;
    }
  }
}

// ---------------------------------------------------------------------------
// Combine split-j partials (JS, bf16) -> bf16 attn [b, l, h*64+dh]
// (separate kernel: reads partials ONCE — R9's fused version re-read them 8x)
// ---------------------------------------------------------------------------
__global__ __launch_bounds__(256) void combine_kernel(const unsigned short* __restrict__ Pb,
                                                      const float* __restrict__ rsbuf,
                                                      unsigned short* __restrict__ attnb) {
  int idx = blockIdx.x * 256 + threadIdx.x;       // over RG_TOT*16 ushort4 chunks
  int rg = idx >> 4, c4 = idx & 15;
  float s0 = 0.f, s1 = 0.f, s2 = 0.f, s3 = 0.f, rsum = 0.f;
#pragma unroll
  for (int js = 0; js < JS; ++js) {
    ushort4 u = *(const ushort4*)&Pb[((size_t)js * RG_TOT + rg) * DH + c4 * 4];
    s0 += bf2f(u.x); s1 += bf2f(u.y); s2 += bf2f(u.z); s3 += bf2f(u.w);
    rsum += rsbuf[(size_t)js * RG_TOT + rg];
  }
  float rs = 1.0f / rsum;
  int bhm = rg >> 11;           // b*8+h
  int l   = rg & 2047;
  int bb  = bhm >> 3, hh = bhm & 7;
  ushort4 o;
  o.x = f2bf(s0 * rs);
  o.y = f2bf(s1 * rs);
  o.z = f2bf(s2 * rs);
  o.w = f2bf(s3 * rs);
  *(ushort4*)&attnb[(((size_t)bb * NL + l) * ND) + hh * DH + c4 * 4] = o;
}

// ---------------------------------------------------------------------------
// Output GEMM (64x128 tiles, 256 blocks): A=w_out rows, B=attn tokens.
// Both operands staged via global_load_lds; clean float4 epilogue + bias.
// ---------------------------------------------------------------------------
__global__ __launch_bounds__(256, 2) void gemm_out(
    const unsigned short* __restrict__ A, const unsigned short* __restrict__ Bm,
    const float* __restrict__ bias, float* __restrict__ out)
{
  __shared__ __align__(16) unsigned short S[64 * 32 + 128 * 32];  // A | B
  const int tid = threadIdx.x, wid = tid >> 6, lane = tid & 63;
  const int quad = lane >> 4, l15 = lane & 15;
  const int m0 = blockIdx.x * 64, n0 = blockIdx.y * 128;
  const int wm = (wid >> 1) * 32, wn = (wid & 1) * 64;

  f32x4 acc[2][4];
#pragma unroll
  for (int a = 0; a < 2; ++a)
#pragma unroll
    for (int b = 0; b < 4; ++b)
#pragma unroll
      for (int z = 0; z < 4; ++z) acc[a][b][z] = 0.f;

  for (int k0 = 0; k0 < ND; k0 += 32) {
#pragma unroll
    for (int p = 0; p < 3; ++p) {
      int c = p * 256 + wid * 64 + lane;
      if (c < 256) {
        int row = c >> 2, off = c & 3;
        gl_lds16(A + (size_t)(m0 + row) * ND + k0 + off * 8, &S[c * 8]);
      } else {
        int cb = c - 256;
        int row = cb >> 2, off = cb & 3;
        gl_lds16(Bm + (size_t)(n0 + row) * ND + k0 + off * 8, &S[2048 + cb * 8]);
      }
    }
    __syncthreads();
    bf16x8 af[2], bfr[4];
#pragma unroll
    for (int mb = 0; mb < 2; ++mb)
      af[mb] = *(const bf16x8*)&S[(wm + mb * 16 + l15) * 32 + quad * 8];
#pragma unroll
    for (int nb = 0; nb < 4; ++nb)
      bfr[nb] = *(const bf16x8*)&S[2048 + (wn + nb * 16 + l15) * 32 + quad * 8];
#pragma unroll
    for (int mb = 0; mb < 2; ++mb)
#pragma unroll
      for (int nb = 0; nb < 4; ++nb)
        acc[mb][nb] = __builtin_amdgcn_mfma_f32_16x16x32_bf16(af[mb], bfr[nb], acc[mb][nb], 0, 0, 0);
    __syncthreads();
  }

#pragma unroll
  for (int mb = 0; mb < 2; ++mb) {
    int e0 = m0 + wm + mb * 16 + quad * 4;
    float4 bv = *(const float4*)&bias[e0];
#pragma unroll
    for (int nb = 0; nb < 4; ++nb) {
      int token = n0 + wn + nb * 16 + l15;
      float4 o;
      o.x = acc[mb][nb][0] + bv.x;
      o.y = acc[mb][nb][1] + bv.y;
      o.z = acc[mb][nb][2] + bv.z;
      o.w = acc[mb][nb][3] + bv.w;
      *(float4*)&out[(size_t)token * ND + e0] = o;
    }
  }
}

// ---------------------------------------------------------------------------
extern "C" void kernel_launch(void* const* d_in, const int* in_sizes, int n_in,
                              void* d_out, int out_size, void* d_ws, size_t ws_size,
                              hipStream_t stream) {
  const float* x         = (const float*)d_in[0];
  const float* positions = (const float*)d_in[1];
  const float* w_qkv     = (const float*)d_in[2];
  const float* w_out     = (const float*)d_in[3];
  const float* b_out     = (const float*)d_in[4];
  const float* log_sigma = (const float*)d_in[5];
  const float* gbias     = (const float*)d_in[6];
  const int*   ns        = (const int*)d_in[7];

  // workspace layout (shorts unless noted); lifetime overlap:
  //   region R: [wqb] (dead after gemm_qkv) overlapped by [Pb | rsbuf]
  //   xb (x bf16) dead after gemm_qkv -> reused as attn bf16
  unsigned short* ws   = (unsigned short*)d_ws;
  unsigned short* xb   = ws;                   // 2,097,152
  unsigned short* wob  = xb   + 2097152;       //   262,144
  unsigned short* qbf  = wob  + 262144;        // 2,097,152
  unsigned short* kpf  = qbf  + 2097152;       // 2,097,152 (K' frag-major)
  unsigned short* vbf  = kpf  + 2097152;       // 2,097,152 (v row-major)
  unsigned short* vpf  = vbf  + 2097152;       // 2,097,152 (V' frag-major)
  unsigned short* qext = vpf  + 2097152;       // 1,048,576
  unsigned short* kext = qext + 1048576;       // 1,048,576
  float* pospad = (float*)(kext + 1048576);    // NB*2048*2 f32
  unsigned short* R    = (unsigned short*)(pospad + NB * NL * 2);
  unsigned short* wqb  = R;                    //   786,432
  unsigned short* Pb   = R;                    // JS*32768*64 bf16 = 16.8 MB
  float* rsbuf = (float*)(Pb + (size_t)JS * RG_TOT * DH);  // JS*32768 f32

  // 1) f32 -> bf16 + zero-padded positions
  cvt_f32_bf16<<<(TOTC + NB * 1024 + 255) / 256, 256, 0, stream>>>(
      x, w_qkv, w_out, positions, ns, xb, wqb, wob, pospad);

  // 2) QKV projection -> q(scaled) row-major, K' frag-major, v row-major
  dim3 g1((3 * NH * DH) / 128, NB * NL / 128);
  gemm_qkv<<<g1, 256, 0, stream>>>(wqb, xb, qbf, kpf, vbf);

  // 3) V' repack + bias-ext builders (k_ext, q_ext)
  dim3 gr(NL / 64, NB * NH);
  repack_v<<<gr, 256, 0, stream>>>(vbf, vpf, pospad, log_sigma, gbias, ns, kext, qext);

  // 4) flash attention partials (split-j=4, barrier-free, ext-bias MFMA)
  dim3 g2((NL / 128) * JS, NH, NB);
  flash_kernel<<<g2, 256, 0, stream>>>(qbf, qext, kpf, kext, vpf, gbias, Pb, rsbuf);

  // 5) combine -> bf16 attn (into xb; reads partials exactly once)
  combine_kernel<<<RG_TOT * 16 / 256, 256, 0, stream>>>(Pb, rsbuf, xb);

  // 6) output projection (+bias) -> f32 d_out
  dim3 g3(ND / 64, NB * NL / 128);
  gemm_out<<<g3, 256, 0, stream>>>(wob, xb, b_out, (float*)d_out);
}

// Round 11
// 146.613 us; speedup vs baseline: 1.1388x; 1.0420x over previous
//
#include <hip/hip_runtime.h>
#include <stdint.h>
#include <stddef.h>

// Problem constants (fixed by setup_inputs)
#define NB   2      // batch
#define NL   2048   // seq len
#define ND   512    // model dim
#define NH   8      // heads
#define DH   64     // dim head
#define LOG2E 1.44269504f
#define RG_TOT 32768  // NB*NH*NL rows of partials
#define JS   4      // split-j factor

typedef __attribute__((ext_vector_type(8))) short bf16x8;
typedef __attribute__((ext_vector_type(4))) float f32x4;

__device__ __forceinline__ unsigned short f2bf(float f) {
  union { float f; unsigned int u; } c; c.f = f;
  unsigned int u = c.u;
  unsigned int r = u + 0x7fffu + ((u >> 16) & 1u);
  return (unsigned short)(r >> 16);
}

__device__ __forceinline__ float bf2f(unsigned short u) {
  union { unsigned int i; float f; } c; c.i = ((unsigned int)u) << 16; return c.f;
}

// hi/lo bf16 split: hi+lo == v to ~2^-16 relative
__device__ __forceinline__ void split2(float v, unsigned short& h, unsigned short& l) {
  h = f2bf(v);
  l = f2bf(v - bf2f(h));
}

__device__ __forceinline__ float fexp2(float x) {
#if __has_builtin(__builtin_amdgcn_exp2f)
  return __builtin_amdgcn_exp2f(x);
#else
  return exp2f(x);
#endif
}

// async global->LDS 16B copy; lanes of a wave must target base + lane*16
__device__ __forceinline__ void gl_lds16(const unsigned short* g, unsigned short* l) {
#if __has_builtin(__builtin_amdgcn_global_load_lds)
  __builtin_amdgcn_global_load_lds(
      (const __attribute__((address_space(1))) unsigned int*)g,
      (__attribute__((address_space(3))) unsigned int*)l, 16, 0, 0);
#else
  *(uint4*)l = *(const uint4*)g;
#endif
}

// ---------------------------------------------------------------------------
// cvt + ext-bias builders (repack_v's non-V work folded in; pospad removed).
// Section A: f32->bf16 for x, w_qkv, w_out.
// Section B: k_ext frag-major, (bh*128 + jt)*512 + (quad*16 + j&15)*8
// Section C: q_ext row-major,  (bh*NL + i)*32 + d
// Bias bilinear decomposition (log2 units), CI=log2e/(2 sig^2), LGB=log2e*gb:
//   d0,1: a=split(riCm)   b=1,1        (riCm=-CI|pi|^2-LGB, zeroed if i>=Ls)
//   d2,3: a=1,1           b=split(rjC) (rjC=-CI|pj|^2, zeroed if j>=Ls)
//   d4,5,6: a=(xh,xl,xh)  b=(Xh,Xh,Xl) (x=pix, X=2CI*pjx)
//   d7,8,9: same for y;   dims 10..31 zero
// ---------------------------------------------------------------------------
#define XC  524288   // 4096*512/4
#define WQC 196608   // 1536*512/4
#define WOC 65536    // 512*512/4
#define TOTC (XC + WQC + WOC)
__global__ void cvt_ext(const float* __restrict__ x, const float* __restrict__ wq,
                        const float* __restrict__ wo, const float* __restrict__ positions,
                        const float* __restrict__ log_sigma, const float* __restrict__ gbias_p,
                        const int* __restrict__ ns_p,
                        unsigned short* __restrict__ xb, unsigned short* __restrict__ wqb,
                        unsigned short* __restrict__ wob,
                        unsigned short* __restrict__ kext, unsigned short* __restrict__ qext) {
  int idx = blockIdx.x * 256 + threadIdx.x;
  if (idx < TOTC) {
    const float* src; unsigned short* dst; int off;
    if (idx < XC)            { src = x;  dst = xb;  off = idx; }
    else if (idx < XC + WQC) { src = wq; dst = wqb; off = idx - XC; }
    else                     { src = wo; dst = wob; off = idx - XC - WQC; }
    float4 f = ((const float4*)src)[off];
    ushort4 o;
    o.x = f2bf(f.x); o.y = f2bf(f.y); o.z = f2bf(f.z); o.w = f2bf(f.w);
    ((ushort4*)dst)[off] = o;
    return;
  }
  int t2 = idx - TOTC;          // [0, 65536)
  int bh = (t2 >> 11) & 15;
  int j  = t2 & 2047;
  int b  = bh >> 3, h = bh & 7;
  int Ls = ns_p[0];
  float sig = __expf(log_sigma[h]);
  float CI  = LOG2E * 0.5f / (sig * sig);
  uint4 z = make_uint4(0u, 0u, 0u, 0u);
  if (t2 < 32768) {
    // Section B: k_ext
    unsigned short bv[16];
#pragma unroll
    for (int q = 0; q < 16; ++q) bv[q] = 0;
    if (j < Ls) {
      float px = positions[((size_t)b * Ls + j) * 2];
      float py = positions[((size_t)b * Ls + j) * 2 + 1];
      float rjC = -(CI * (px * px + py * py));
      unsigned short one = f2bf(1.0f);
      bv[0] = one; bv[1] = one;
      split2(rjC, bv[2], bv[3]);
      unsigned short Xh, Xl, Yh, Yl;
      split2(2.0f * CI * px, Xh, Xl);
      split2(2.0f * CI * py, Yh, Yl);
      bv[4] = Xh; bv[5] = Xh; bv[6] = Xl;
      bv[7] = Yh; bv[8] = Yh; bv[9] = Yl;
    }
    unsigned short* kx = kext + ((size_t)bh * 128 + (j >> 4)) * 512 + (size_t)(j & 15) * 8;
    *(uint4*)(kx)       = *(uint4*)&bv[0];
    *(uint4*)(kx + 128) = *(uint4*)&bv[8];
    *(uint4*)(kx + 256) = z;
    *(uint4*)(kx + 384) = z;
  } else {
    // Section C: q_ext
    unsigned short av[16];
#pragma unroll
    for (int q = 0; q < 16; ++q) av[q] = 0;
    if (j < Ls) {
      float px = positions[((size_t)b * Ls + j) * 2];
      float py = positions[((size_t)b * Ls + j) * 2 + 1];
      float LGB = LOG2E * gbias_p[0];
      float riCm = -(CI * (px * px + py * py)) - LGB;
      unsigned short one = f2bf(1.0f);
      split2(riCm, av[0], av[1]);
      av[2] = one; av[3] = one;
      unsigned short xh, xl, yh, yl;
      split2(px, xh, xl);
      split2(py, yh, yl);
      av[4] = xh; av[5] = xl; av[6] = xh;
      av[7] = yh; av[8] = yl; av[9] = yh;
    }
    unsigned short* qx = qext + ((size_t)bh * NL + j) * 32;
    *(uint4*)(qx)      = *(uint4*)&av[0];
    *(uint4*)(qx + 8)  = *(uint4*)&av[8];
    *(uint4*)(qx + 16) = z;
    *(uint4*)(qx + 24) = z;
  }
}

// ---------------------------------------------------------------------------
// QKV GEMM (128x128 tiles, m97 structure), SWAPPED: A=w_qkv rows, B=tokens.
//   q: pre-scaled by 0.125*log2e, row-major [b,h,l,dh] (ushort4)
//   k: FRAGMENT-MAJOR K': ((bh*128 + jt)*2 + kc)*512 + lane*8 shorts
//   v: FRAGMENT-MAJOR V' (fused repack, direct scalar stores):
//      ((bh*64 + l>>5)*4 + dht)*512 + ((l>>3)&3)*128 + (dh&15)*8 + (l&7)
// ---------------------------------------------------------------------------
__global__ __launch_bounds__(256, 2) void gemm_qkv(
    const unsigned short* __restrict__ A, const unsigned short* __restrict__ Bm,
    unsigned short* __restrict__ qo, unsigned short* __restrict__ kp,
    unsigned short* __restrict__ vp)
{
  __shared__ __align__(16) unsigned short S[128 * 32 + 128 * 32];
  const int tid = threadIdx.x, wid = tid >> 6, lane = tid & 63;
  const int quad = lane >> 4, l15 = lane & 15;
  const int m0 = blockIdx.x * 128, n0 = blockIdx.y * 128;
  const int wm = (wid >> 1) * 64, wn = (wid & 1) * 64;

  f32x4 acc[4][4];
#pragma unroll
  for (int a = 0; a < 4; ++a)
#pragma unroll
    for (int b = 0; b < 4; ++b)
#pragma unroll
      for (int z = 0; z < 4; ++z) acc[a][b][z] = 0.f;

  for (int k0 = 0; k0 < ND; k0 += 32) {
#pragma unroll
    for (int p = 0; p < 4; ++p) {
      int c = p * 256 + wid * 64 + lane;
      if (c < 512) {
        int row = c >> 2, off = c & 3;
        gl_lds16(A + (size_t)(m0 + row) * ND + k0 + off * 8, &S[c * 8]);
      } else {
        int cb = c - 512;
        int row = cb >> 2, off = cb & 3;
        gl_lds16(Bm + (size_t)(n0 + row) * ND + k0 + off * 8, &S[c * 8]);
      }
    }
    __syncthreads();
    bf16x8 af[4], bfr[4];
#pragma unroll
    for (int mb = 0; mb < 4; ++mb)
      af[mb] = *(const bf16x8*)&S[(wm + mb * 16 + l15) * 32 + quad * 8];
#pragma unroll
    for (int nb = 0; nb < 4; ++nb)
      bfr[nb] = *(const bf16x8*)&S[4096 + (wn + nb * 16 + l15) * 32 + quad * 8];
#pragma unroll
    for (int mb = 0; mb < 4; ++mb)
#pragma unroll
      for (int nb = 0; nb < 4; ++nb)
        acc[mb][nb] = __builtin_amdgcn_mfma_f32_16x16x32_bf16(af[mb], bfr[nb], acc[mb][nb], 0, 0, 0);
    __syncthreads();
  }

  const float QSCALE = 0.125f * LOG2E;
#pragma unroll
  for (int mb = 0; mb < 4; ++mb) {
    int e0 = m0 + wm + mb * 16 + quad * 4;
    int s   = e0 >> 9;
    int hh  = (e0 >> 6) & 7;
    if (s == 1) {
      int kc  = mb >> 1;
      int q_t = ((mb & 1) << 1) + (quad >> 1);
      int par = quad & 1;
#pragma unroll
      for (int nb = 0; nb < 4; ++nb) {
        int token = n0 + wn + nb * 16 + l15;
        int bb = token >> 11, ll = token & 2047;
        int jt = ll >> 4;
        ushort4 o;
        o.x = f2bf(acc[mb][nb][0]);
        o.y = f2bf(acc[mb][nb][1]);
        o.z = f2bf(acc[mb][nb][2]);
        o.w = f2bf(acc[mb][nb][3]);
        size_t addr = (((size_t)(bb * NH + hh) * 128 + jt) * 2 + kc) * 512
                    + (q_t * 16 + l15) * 8 + par * 4;
        *(ushort4*)&kp[addr] = o;
      }
    } else if (s == 2) {
      // fused V' fragment repack (8 consecutive lanes hit 16 contiguous B)
      int dh0 = e0 & 63;
      int dht = dh0 >> 4;
      int dl  = dh0 & 15;         // = quad*4
#pragma unroll
      for (int nb = 0; nb < 4; ++nb) {
        int token = n0 + wn + nb * 16 + l15;
        int bb = token >> 11, ll = token & 2047;
        size_t base = (((size_t)(bb * NH + hh) * 64 + (ll >> 5)) * 4 + dht) * 512
                    + (size_t)(((ll >> 3) & 3)) * 128 + (ll & 7);
#pragma unroll
        for (int r = 0; r < 4; ++r)
          vp[base + (size_t)(dl + r) * 8] = f2bf(acc[mb][nb][r]);
      }
    } else {
      int dh0 = e0 & 63;
#pragma unroll
      for (int nb = 0; nb < 4; ++nb) {
        int token = n0 + wn + nb * 16 + l15;
        int bb = token >> 11, ll = token & 2047;
        ushort4 o;
        o.x = f2bf(acc[mb][nb][0] * QSCALE);
        o.y = f2bf(acc[mb][nb][1] * QSCALE);
        o.z = f2bf(acc[mb][nb][2] * QSCALE);
        o.w = f2bf(acc[mb][nb][3] * QSCALE);
        *(ushort4*)&qo[(((size_t)bb * NH + hh) * NL + ll) * DH + dh0] = o;
      }
    }
  }
}

// ---------------------------------------------------------------------------
// Flash attention (R9-verified math): S^T orientation, barrier-free,
// frag-direct K'/K_ext/V' loads, bias folded into a 3rd MFMA. softmax body =
// add + exp2 + add + pack. P: b64 stores / b128 loads, wave-private LDS.
// Split-j=JS partials (bf16 accO + f32 rsum).
// launch_bounds(256,3): cap ~170 VGPR -> 3 waves/SIMD (R6's forced-4 at 128
// spilled; audit says ~160 live max here).
// ---------------------------------------------------------------------------
__global__ __launch_bounds__(256, 3) void flash_kernel(
    const unsigned short* __restrict__ qb, const unsigned short* __restrict__ qeb,
    const unsigned short* __restrict__ kp, const unsigned short* __restrict__ keb,
    const unsigned short* __restrict__ vp, const float* __restrict__ gbias_p,
    unsigned short* __restrict__ Pb, float* __restrict__ rsbuf)
{
  const int it = blockIdx.x >> 2;       // 0..15
  const int js = blockIdx.x & 3;        // 0..3
  const int h  = blockIdx.y;
  const int b  = blockIdx.z;
  const int i0 = it * 128;
  const int jbase = js * (NL / JS);     // 512 j per block
  const float CBL = -8.0f * LOG2E + LOG2E * gbias_p[0];

  const int tid  = threadIdx.x;
  const int wid  = tid >> 6;      // 0..3
  const int lane = tid & 63;
  const int quad = lane >> 4;
  const int l15  = lane & 15;

  __shared__ __align__(16) unsigned short Ps[128][78];   // wave-private rows

  const size_t bh = (size_t)b * NH + h;
  const unsigned short* qbase  = qb  + (bh * NL + i0 + wid * 32) * DH;
  const unsigned short* qebase = qeb + (bh * NL + i0 + wid * 32) * 32;
  const unsigned short* kpb    = kp  + bh * 131072;
  const unsigned short* kebb   = keb + bh * 65536;
  const unsigned short* vpb    = vp  + bh * 131072;

  // Q B-frags (lane l15 = i) + ext
  bf16x8 qf[2][2], qfe[2];
#pragma unroll
  for (int ib = 0; ib < 2; ++ib) {
#pragma unroll
    for (int kc = 0; kc < 2; ++kc)
      qf[ib][kc] = *(const bf16x8*)(qbase + (size_t)(ib * 16 + l15) * DH + kc * 32 + quad * 8);
    qfe[ib] = *(const bf16x8*)(qebase + (size_t)(ib * 16 + l15) * 32 + quad * 8);
  }

  f32x4 accO[4][2];   // [dht][ib]; C row = dh, col = i
  float rsum[2];
#pragma unroll
  for (int d = 0; d < 4; ++d)
#pragma unroll
    for (int ib = 0; ib < 2; ++ib)
#pragma unroll
      for (int z = 0; z < 4; ++z) accO[d][ib][z] = 0.f;
  rsum[0] = 0.f; rsum[1] = 0.f;

  for (int jt = 0; jt < NL / JS / 64; ++jt) {
    const int j0 = jbase + jt * 64;
    const int jt0 = j0 >> 4;

    // V' frags (lane = dh-major) — issue early, consumed after softmax
    bf16x8 vf[4][2];
#pragma unroll
    for (int dht = 0; dht < 4; ++dht)
#pragma unroll
      for (int jc = 0; jc < 2; ++jc)
        vf[dht][jc] = *(const bf16x8*)(vpb + ((size_t)((j0 >> 5) + jc) * 4 + dht) * 512 + lane * 8);

    // per j-block: S^T = K Q^T (+ bias via ext dims), softmax, b64 P store
#pragma unroll
    for (int jb = 0; jb < 4; ++jb) {
      bf16x8 kf0 = *(const bf16x8*)(kpb + ((size_t)(jt0 + jb) * 2 + 0) * 512 + lane * 8);
      bf16x8 kf1 = *(const bf16x8*)(kpb + ((size_t)(jt0 + jb) * 2 + 1) * 512 + lane * 8);
      bf16x8 kfe = *(const bf16x8*)(kebb + (size_t)(jt0 + jb) * 512 + lane * 8);
#pragma unroll
      for (int ib = 0; ib < 2; ++ib) {
        f32x4 accS;
#pragma unroll
        for (int z = 0; z < 4; ++z) accS[z] = 0.f;
        accS = __builtin_amdgcn_mfma_f32_16x16x32_bf16(kf0, qf[ib][0], accS, 0, 0, 0);
        accS = __builtin_amdgcn_mfma_f32_16x16x32_bf16(kf1, qf[ib][1], accS, 0, 0, 0);
        accS = __builtin_amdgcn_mfma_f32_16x16x32_bf16(kfe, qfe[ib], accS, 0, 0, 0);
        float p0 = fexp2(accS[0] + CBL);
        float p1 = fexp2(accS[1] + CBL);
        float p2 = fexp2(accS[2] + CBL);
        float p3 = fexp2(accS[3] + CBL);
        rsum[ib] += (p0 + p1) + (p2 + p3);
        uint2 w;
        w.x = (uint32_t)f2bf(p0) | ((uint32_t)f2bf(p1) << 16);
        w.y = (uint32_t)f2bf(p2) | ((uint32_t)f2bf(p3) << 16);
        *(uint2*)&Ps[wid * 32 + ib * 16 + l15][jb * 16 + quad * 4] = w;
      }
    }

    // O^T += V^T P^T (wave-private Ps rows; same-wave lgkm ordering)
    bf16x8 pf[2][2];
#pragma unroll
    for (int ib = 0; ib < 2; ++ib)
#pragma unroll
      for (int jc = 0; jc < 2; ++jc)
        pf[ib][jc] = *(const bf16x8*)&Ps[wid * 32 + ib * 16 + l15][jc * 32 + quad * 8];
#pragma unroll
    for (int dht = 0; dht < 4; ++dht)
#pragma unroll
      for (int ib = 0; ib < 2; ++ib) {
        accO[dht][ib] = __builtin_amdgcn_mfma_f32_16x16x32_bf16(vf[dht][0], pf[ib][0], accO[dht][ib], 0, 0, 0);
        accO[dht][ib] = __builtin_amdgcn_mfma_f32_16x16x32_bf16(vf[dht][1], pf[ib][1], accO[dht][ib], 0, 0, 0);
      }
  }

  // ---- epilogue: unnormalized partials (bf16 accO, f32 rsum) ----
  const size_t rgbase = bh * NL + i0;
  const size_t poff = (size_t)js * RG_TOT * DH;
#pragma unroll
  for (int ib = 0; ib < 2; ++ib) {
    float v = rsum[ib];
    v += __shfl_xor(v, 16);
    v += __shfl_xor(v, 32);
    int irow = wid * 32 + ib * 16 + l15;
    if (quad == 0)
      rsbuf[(size_t)js * RG_TOT + rgbase + irow] = v;
#pragma unroll
    for (int dht = 0; dht < 4; ++dht) {
      ushort4 o;
      o.x = f2bf(accO[dht][ib][0]);
      o.y = f2bf(accO[dht][ib][1]);
      o.z = f2bf(accO[dht][ib][2]);
      o.w = f2bf(accO[dht][ib][3]);
      *(ushort4*)&Pb[poff + (rgbase + irow) * DH + dht * 16 + quad * 4] = o;
    }
  }
}

// ---------------------------------------------------------------------------
// Combine split-j partials (JS, bf16) -> bf16 attn [b, l, h*64+dh]
// ---------------------------------------------------------------------------
__global__ __launch_bounds__(256) void combine_kernel(const unsigned short* __restrict__ Pb,
                                                      const float* __restrict__ rsbuf,
                                                      unsigned short* __restrict__ attnb) {
  int idx = blockIdx.x * 256 + threadIdx.x;       // over RG_TOT*16 ushort4 chunks
  int rg = idx >> 4, c4 = idx & 15;
  float s0 = 0.f, s1 = 0.f, s2 = 0.f, s3 = 0.f, rsum = 0.f;
#pragma unroll
  for (int js = 0; js < JS; ++js) {
    ushort4 u = *(const ushort4*)&Pb[((size_t)js * RG_TOT + rg) * DH + c4 * 4];
    s0 += bf2f(u.x); s1 += bf2f(u.y); s2 += bf2f(u.z); s3 += bf2f(u.w);
    rsum += rsbuf[(size_t)js * RG_TOT + rg];
  }
  float rs = 1.0f / rsum;
  int bhm = rg >> 11;           // b*8+h
  int l   = rg & 2047;
  int bb  = bhm >> 3, hh = bhm & 7;
  ushort4 o;
  o.x = f2bf(s0 * rs);
  o.y = f2bf(s1 * rs);
  o.z = f2bf(s2 * rs);
  o.w = f2bf(s3 * rs);
  *(ushort4*)&attnb[(((size_t)bb * NL + l) * ND) + hh * DH + c4 * 4] = o;
}

// ---------------------------------------------------------------------------
// Output GEMM (64x128 tiles, 256 blocks): A=w_out rows, B=attn tokens.
// Both operands staged via global_load_lds; clean float4 epilogue + bias.
// ---------------------------------------------------------------------------
__global__ __launch_bounds__(256, 2) void gemm_out(
    const unsigned short* __restrict__ A, const unsigned short* __restrict__ Bm,
    const float* __restrict__ bias, float* __restrict__ out)
{
  __shared__ __align__(16) unsigned short S[64 * 32 + 128 * 32];  // A | B
  const int tid = threadIdx.x, wid = tid >> 6, lane = tid & 63;
  const int quad = lane >> 4, l15 = lane & 15;
  const int m0 = blockIdx.x * 64, n0 = blockIdx.y * 128;
  const int wm = (wid >> 1) * 32, wn = (wid & 1) * 64;

  f32x4 acc[2][4];
#pragma unroll
  for (int a = 0; a < 2; ++a)
#pragma unroll
    for (int b = 0; b < 4; ++b)
#pragma unroll
      for (int z = 0; z < 4; ++z) acc[a][b][z] = 0.f;

  for (int k0 = 0; k0 < ND; k0 += 32) {
#pragma unroll
    for (int p = 0; p < 3; ++p) {
      int c = p * 256 + wid * 64 + lane;
      if (c < 256) {
        int row = c >> 2, off = c & 3;
        gl_lds16(A + (size_t)(m0 + row) * ND + k0 + off * 8, &S[c * 8]);
      } else {
        int cb = c - 256;
        int row = cb >> 2, off = cb & 3;
        gl_lds16(Bm + (size_t)(n0 + row) * ND + k0 + off * 8, &S[2048 + cb * 8]);
      }
    }
    __syncthreads();
    bf16x8 af[2], bfr[4];
#pragma unroll
    for (int mb = 0; mb < 2; ++mb)
      af[mb] = *(const bf16x8*)&S[(wm + mb * 16 + l15) * 32 + quad * 8];
#pragma unroll
    for (int nb = 0; nb < 4; ++nb)
      bfr[nb] = *(const bf16x8*)&S[2048 + (wn + nb * 16 + l15) * 32 + quad * 8];
#pragma unroll
    for (int mb = 0; mb < 2; ++mb)
#pragma unroll
      for (int nb = 0; nb < 4; ++nb)
        acc[mb][nb] = __builtin_amdgcn_mfma_f32_16x16x32_bf16(af[mb], bfr[nb], acc[mb][nb], 0, 0, 0);
    __syncthreads();
  }

#pragma unroll
  for (int mb = 0; mb < 2; ++mb) {
    int e0 = m0 + wm + mb * 16 + quad * 4;
    float4 bv = *(const float4*)&bias[e0];
#pragma unroll
    for (int nb = 0; nb < 4; ++nb) {
      int token = n0 + wn + nb * 16 + l15;
      float4 o;
      o.x = acc[mb][nb][0] + bv.x;
      o.y = acc[mb][nb][1] + bv.y;
      o.z = acc[mb][nb][2] + bv.z;
      o.w = acc[mb][nb][3] + bv.w;
      *(float4*)&out[(size_t)token * ND + e0] = o;
    }
  }
}

// ---------------------------------------------------------------------------
extern "C" void kernel_launch(void* const* d_in, const int* in_sizes, int n_in,
                              void* d_out, int out_size, void* d_ws, size_t ws_size,
                              hipStream_t stream) {
  const float* x         = (const float*)d_in[0];
  const float* positions = (const float*)d_in[1];
  const float* w_qkv     = (const float*)d_in[2];
  const float* w_out     = (const float*)d_in[3];
  const float* b_out     = (const float*)d_in[4];
  const float* log_sigma = (const float*)d_in[5];
  const float* gbias     = (const float*)d_in[6];
  const int*   ns        = (const int*)d_in[7];

  // workspace layout (shorts unless noted); lifetime overlap:
  //   region R: [wqb] (dead after gemm_qkv) overlapped by [Pb | rsbuf]
  //   xb (x bf16) dead after gemm_qkv -> reused as attn bf16
  unsigned short* ws   = (unsigned short*)d_ws;
  unsigned short* xb   = ws;                   // 2,097,152
  unsigned short* wob  = xb   + 2097152;       //   262,144
  unsigned short* qbf  = wob  + 262144;        // 2,097,152
  unsigned short* kpf  = qbf  + 2097152;       // 2,097,152 (K' frag-major)
  unsigned short* vpf  = kpf  + 2097152;       // 2,097,152 (V' frag-major)
  unsigned short* qext = vpf  + 2097152;       // 1,048,576
  unsigned short* kext = qext + 1048576;       // 1,048,576
  unsigned short* R    = kext + 1048576;
  unsigned short* wqb  = R;                    //   786,432
  unsigned short* Pb   = R;                    // JS*32768*64 bf16 = 16.8 MB
  float* rsbuf = (float*)(Pb + (size_t)JS * RG_TOT * DH);  // JS*32768 f32

  // 1) f32 -> bf16 + bias-ext builders (k_ext, q_ext)
  cvt_ext<<<(TOTC + 65536) / 256, 256, 0, stream>>>(
      x, w_qkv, w_out, positions, log_sigma, gbias, ns, xb, wqb, wob, kext, qext);

  // 2) QKV projection -> q(scaled) row-major, K' frag-major, V' frag-major
  dim3 g1((3 * NH * DH) / 128, NB * NL / 128);
  gemm_qkv<<<g1, 256, 0, stream>>>(wqb, xb, qbf, kpf, vpf);

  // 3) flash attention partials (split-j=4, barrier-free, ext-bias MFMA)
  dim3 g2((NL / 128) * JS, NH, NB);
  flash_kernel<<<g2, 256, 0, stream>>>(qbf, qext, kpf, kext, vpf, gbias, Pb, rsbuf);

  // 4) combine -> bf16 attn (into xb; reads partials exactly once)
  combine_kernel<<<RG_TOT * 16 / 256, 256, 0, stream>>>(Pb, rsbuf, xb);

  // 5) output projection (+bias) -> f32 d_out
  dim3 g3(ND / 64, NB * NL / 128);
  gemm_out<<<g3, 256, 0, stream>>>(wob, xb, b_out, (float*)d_out);
}

// Round 12
// 144.104 us; speedup vs baseline: 1.1586x; 1.0174x over previous
//
#include <hip/hip_runtime.h>
#include <stdint.h>
#include <stddef.h>

// Problem constants (fixed by setup_inputs)
#define NB   2      // batch
#define NL   2048   // seq len
#define ND   512    // model dim
#define NH   8      // heads
#define DH   64     // dim head
#define LOG2E 1.44269504f
#define RG_TOT 32768  // NB*NH*NL rows of partials
#define JS   4      // split-j factor

typedef __attribute__((ext_vector_type(8))) short bf16x8;
typedef __attribute__((ext_vector_type(4))) float f32x4;

__device__ __forceinline__ unsigned short f2bf(float f) {
  union { float f; unsigned int u; } c; c.f = f;
  unsigned int u = c.u;
  unsigned int r = u + 0x7fffu + ((u >> 16) & 1u);
  return (unsigned short)(r >> 16);
}

__device__ __forceinline__ float bf2f(unsigned short u) {
  union { unsigned int i; float f; } c; c.i = ((unsigned int)u) << 16; return c.f;
}

// hi/lo bf16 split: hi+lo == v to ~2^-16 relative
__device__ __forceinline__ void split2(float v, unsigned short& h, unsigned short& l) {
  h = f2bf(v);
  l = f2bf(v - bf2f(h));
}

__device__ __forceinline__ float fexp2(float x) {
#if __has_builtin(__builtin_amdgcn_exp2f)
  return __builtin_amdgcn_exp2f(x);
#else
  return exp2f(x);
#endif
}

// async global->LDS 16B copy; lanes of a wave must target base + lane*16
__device__ __forceinline__ void gl_lds16(const unsigned short* g, unsigned short* l) {
#if __has_builtin(__builtin_amdgcn_global_load_lds)
  __builtin_amdgcn_global_load_lds(
      (const __attribute__((address_space(1))) unsigned int*)g,
      (__attribute__((address_space(3))) unsigned int*)l, 16, 0, 0);
#else
  *(uint4*)l = *(const uint4*)g;
#endif
}

// ---------------------------------------------------------------------------
// cvt + ext-bias builders.
// Section A: f32->bf16 for x, w_qkv, w_out.
// Section B: k_ext frag-major; Section C: q_ext row-major.
// Bias bilinear decomposition (log2 units), CI=log2e/(2 sig^2), LGB=log2e*gb:
//   d0,1: a=split(riCm)   b=1,1        (riCm=-CI|pi|^2-LGB, zeroed if i>=Ls)
//   d2,3: a=1,1           b=split(rjC) (rjC=-CI|pj|^2, zeroed if j>=Ls)
//   d4,5,6: a=(xh,xl,xh)  b=(Xh,Xh,Xl) (x=pix, X=2CI*pjx)
//   d7,8,9: same for y;   dims 10..31 zero
// ---------------------------------------------------------------------------
#define XC  524288   // 4096*512/4
#define WQC 196608   // 1536*512/4
#define WOC 65536    // 512*512/4
#define TOTC (XC + WQC + WOC)
__global__ void cvt_ext(const float* __restrict__ x, const float* __restrict__ wq,
                        const float* __restrict__ wo, const float* __restrict__ positions,
                        const float* __restrict__ log_sigma, const float* __restrict__ gbias_p,
                        const int* __restrict__ ns_p,
                        unsigned short* __restrict__ xb, unsigned short* __restrict__ wqb,
                        unsigned short* __restrict__ wob,
                        unsigned short* __restrict__ kext, unsigned short* __restrict__ qext) {
  int idx = blockIdx.x * 256 + threadIdx.x;
  if (idx < TOTC) {
    const float* src; unsigned short* dst; int off;
    if (idx < XC)            { src = x;  dst = xb;  off = idx; }
    else if (idx < XC + WQC) { src = wq; dst = wqb; off = idx - XC; }
    else                     { src = wo; dst = wob; off = idx - XC - WQC; }
    float4 f = ((const float4*)src)[off];
    ushort4 o;
    o.x = f2bf(f.x); o.y = f2bf(f.y); o.z = f2bf(f.z); o.w = f2bf(f.w);
    ((ushort4*)dst)[off] = o;
    return;
  }
  int t2 = idx - TOTC;          // [0, 65536)
  int bh = (t2 >> 11) & 15;
  int j  = t2 & 2047;
  int b  = bh >> 3, h = bh & 7;
  int Ls = ns_p[0];
  float sig = __expf(log_sigma[h]);
  float CI  = LOG2E * 0.5f / (sig * sig);
  uint4 z = make_uint4(0u, 0u, 0u, 0u);
  if (t2 < 32768) {
    // Section B: k_ext
    unsigned short bv[16];
#pragma unroll
    for (int q = 0; q < 16; ++q) bv[q] = 0;
    if (j < Ls) {
      float px = positions[((size_t)b * Ls + j) * 2];
      float py = positions[((size_t)b * Ls + j) * 2 + 1];
      float rjC = -(CI * (px * px + py * py));
      unsigned short one = f2bf(1.0f);
      bv[0] = one; bv[1] = one;
      split2(rjC, bv[2], bv[3]);
      unsigned short Xh, Xl, Yh, Yl;
      split2(2.0f * CI * px, Xh, Xl);
      split2(2.0f * CI * py, Yh, Yl);
      bv[4] = Xh; bv[5] = Xh; bv[6] = Xl;
      bv[7] = Yh; bv[8] = Yh; bv[9] = Yl;
    }
    unsigned short* kx = kext + ((size_t)bh * 128 + (j >> 4)) * 512 + (size_t)(j & 15) * 8;
    *(uint4*)(kx)       = *(uint4*)&bv[0];
    *(uint4*)(kx + 128) = *(uint4*)&bv[8];
    *(uint4*)(kx + 256) = z;
    *(uint4*)(kx + 384) = z;
  } else {
    // Section C: q_ext
    unsigned short av[16];
#pragma unroll
    for (int q = 0; q < 16; ++q) av[q] = 0;
    if (j < Ls) {
      float px = positions[((size_t)b * Ls + j) * 2];
      float py = positions[((size_t)b * Ls + j) * 2 + 1];
      float LGB = LOG2E * gbias_p[0];
      float riCm = -(CI * (px * px + py * py)) - LGB;
      unsigned short one = f2bf(1.0f);
      split2(riCm, av[0], av[1]);
      av[2] = one; av[3] = one;
      unsigned short xh, xl, yh, yl;
      split2(px, xh, xl);
      split2(py, yh, yl);
      av[4] = xh; av[5] = xl; av[6] = xh;
      av[7] = yh; av[8] = yl; av[9] = yh;
    }
    unsigned short* qx = qext + ((size_t)bh * NL + j) * 32;
    *(uint4*)(qx)      = *(uint4*)&av[0];
    *(uint4*)(qx + 8)  = *(uint4*)&av[8];
    *(uint4*)(qx + 16) = z;
    *(uint4*)(qx + 24) = z;
  }
}

// ---------------------------------------------------------------------------
// QKV GEMM, 128x64 tiles (768 blocks = 3/CU: better tail balance than the
// 384-block 128x128 version). A=w_qkv rows, B=tokens.
//   q: pre-scaled by 0.125*log2e, row-major [b,h,l,dh] (ushort4)
//   k: FRAGMENT-MAJOR K': ((bh*128 + jt)*2 + kc)*512 + lane*8 shorts
//   v: FRAGMENT-MAJOR V' (fused repack, direct scalar stores)
// ---------------------------------------------------------------------------
__global__ __launch_bounds__(256, 2) void gemm_qkv(
    const unsigned short* __restrict__ A, const unsigned short* __restrict__ Bm,
    unsigned short* __restrict__ qo, unsigned short* __restrict__ kp,
    unsigned short* __restrict__ vp)
{
  __shared__ __align__(16) unsigned short S[128 * 32 + 64 * 32];  // A | B
  const int tid = threadIdx.x, wid = tid >> 6, lane = tid & 63;
  const int quad = lane >> 4, l15 = lane & 15;
  const int m0 = blockIdx.x * 128, n0 = blockIdx.y * 64;
  const int wm = (wid >> 1) * 64, wn = (wid & 1) * 32;

  f32x4 acc[4][2];
#pragma unroll
  for (int a = 0; a < 4; ++a)
#pragma unroll
    for (int b = 0; b < 2; ++b)
#pragma unroll
      for (int z = 0; z < 4; ++z) acc[a][b][z] = 0.f;

  for (int k0 = 0; k0 < ND; k0 += 32) {
#pragma unroll
    for (int p = 0; p < 3; ++p) {
      int c = p * 256 + wid * 64 + lane;   // 768 chunks: A 512 | B 256
      if (c < 512) {
        int row = c >> 2, off = c & 3;
        gl_lds16(A + (size_t)(m0 + row) * ND + k0 + off * 8, &S[c * 8]);
      } else {
        int cb = c - 512;
        int row = cb >> 2, off = cb & 3;
        gl_lds16(Bm + (size_t)(n0 + row) * ND + k0 + off * 8, &S[4096 + cb * 8]);
      }
    }
    __syncthreads();
    bf16x8 af[4], bfr[2];
#pragma unroll
    for (int mb = 0; mb < 4; ++mb)
      af[mb] = *(const bf16x8*)&S[(wm + mb * 16 + l15) * 32 + quad * 8];
#pragma unroll
    for (int nb = 0; nb < 2; ++nb)
      bfr[nb] = *(const bf16x8*)&S[4096 + (wn + nb * 16 + l15) * 32 + quad * 8];
#pragma unroll
    for (int mb = 0; mb < 4; ++mb)
#pragma unroll
      for (int nb = 0; nb < 2; ++nb)
        acc[mb][nb] = __builtin_amdgcn_mfma_f32_16x16x32_bf16(af[mb], bfr[nb], acc[mb][nb], 0, 0, 0);
    __syncthreads();
  }

  const float QSCALE = 0.125f * LOG2E;
#pragma unroll
  for (int mb = 0; mb < 4; ++mb) {
    int e0 = m0 + wm + mb * 16 + quad * 4;
    int s   = e0 >> 9;
    int hh  = (e0 >> 6) & 7;
    if (s == 1) {
      int kc  = mb >> 1;
      int q_t = ((mb & 1) << 1) + (quad >> 1);
      int par = quad & 1;
#pragma unroll
      for (int nb = 0; nb < 2; ++nb) {
        int token = n0 + wn + nb * 16 + l15;
        int bb = token >> 11, ll = token & 2047;
        int jt = ll >> 4;
        ushort4 o;
        o.x = f2bf(acc[mb][nb][0]);
        o.y = f2bf(acc[mb][nb][1]);
        o.z = f2bf(acc[mb][nb][2]);
        o.w = f2bf(acc[mb][nb][3]);
        size_t addr = (((size_t)(bb * NH + hh) * 128 + jt) * 2 + kc) * 512
                    + (q_t * 16 + l15) * 8 + par * 4;
        *(ushort4*)&kp[addr] = o;
      }
    } else if (s == 2) {
      // fused V' fragment repack
      int dh0 = e0 & 63;
      int dht = dh0 >> 4;
      int dl  = dh0 & 15;         // = quad*4
#pragma unroll
      for (int nb = 0; nb < 2; ++nb) {
        int token = n0 + wn + nb * 16 + l15;
        int bb = token >> 11, ll = token & 2047;
        size_t base = (((size_t)(bb * NH + hh) * 64 + (ll >> 5)) * 4 + dht) * 512
                    + (size_t)(((ll >> 3) & 3)) * 128 + (ll & 7);
#pragma unroll
        for (int r = 0; r < 4; ++r)
          vp[base + (size_t)(dl + r) * 8] = f2bf(acc[mb][nb][r]);
      }
    } else {
      int dh0 = e0 & 63;
#pragma unroll
      for (int nb = 0; nb < 2; ++nb) {
        int token = n0 + wn + nb * 16 + l15;
        int bb = token >> 11, ll = token & 2047;
        ushort4 o;
        o.x = f2bf(acc[mb][nb][0] * QSCALE);
        o.y = f2bf(acc[mb][nb][1] * QSCALE);
        o.z = f2bf(acc[mb][nb][2] * QSCALE);
        o.w = f2bf(acc[mb][nb][3] * QSCALE);
        *(ushort4*)&qo[(((size_t)bb * NH + hh) * NL + ll) * DH + dh0] = o;
      }
    }
  }
}

// ---------------------------------------------------------------------------
// Flash attention (R9/R11-verified): S^T orientation, barrier-free,
// frag-direct K'/K_ext/V' loads, bias folded into a 3rd MFMA. softmax body =
// add + exp2 + add + pack. P: b64 stores / b128 loads, wave-private LDS.
// Split-j=JS partials (bf16 accO + f32 rsum). launch_bounds(256,3) verified
// non-spilling in R11 (total improved; R6's forced-4 at 128 VGPR spilled).
// ---------------------------------------------------------------------------
__global__ __launch_bounds__(256, 3) void flash_kernel(
    const unsigned short* __restrict__ qb, const unsigned short* __restrict__ qeb,
    const unsigned short* __restrict__ kp, const unsigned short* __restrict__ keb,
    const unsigned short* __restrict__ vp, const float* __restrict__ gbias_p,
    unsigned short* __restrict__ Pb, float* __restrict__ rsbuf)
{
  const int it = blockIdx.x >> 2;       // 0..15
  const int js = blockIdx.x & 3;        // 0..3
  const int h  = blockIdx.y;
  const int b  = blockIdx.z;
  const int i0 = it * 128;
  const int jbase = js * (NL / JS);     // 512 j per block
  const float CBL = -8.0f * LOG2E + LOG2E * gbias_p[0];

  const int tid  = threadIdx.x;
  const int wid  = tid >> 6;      // 0..3
  const int lane = tid & 63;
  const int quad = lane >> 4;
  const int l15  = lane & 15;

  __shared__ __align__(16) unsigned short Ps[128][78];   // wave-private rows

  const size_t bh = (size_t)b * NH + h;
  const unsigned short* qbase  = qb  + (bh * NL + i0 + wid * 32) * DH;
  const unsigned short* qebase = qeb + (bh * NL + i0 + wid * 32) * 32;
  const unsigned short* kpb    = kp  + bh * 131072;
  const unsigned short* kebb   = keb + bh * 65536;
  const unsigned short* vpb    = vp  + bh * 131072;

  // Q B-frags (lane l15 = i) + ext
  bf16x8 qf[2][2], qfe[2];
#pragma unroll
  for (int ib = 0; ib < 2; ++ib) {
#pragma unroll
    for (int kc = 0; kc < 2; ++kc)
      qf[ib][kc] = *(const bf16x8*)(qbase + (size_t)(ib * 16 + l15) * DH + kc * 32 + quad * 8);
    qfe[ib] = *(const bf16x8*)(qebase + (size_t)(ib * 16 + l15) * 32 + quad * 8);
  }

  f32x4 accO[4][2];   // [dht][ib]; C row = dh, col = i
  float rsum[2];
#pragma unroll
  for (int d = 0; d < 4; ++d)
#pragma unroll
    for (int ib = 0; ib < 2; ++ib)
#pragma unroll
      for (int z = 0; z < 4; ++z) accO[d][ib][z] = 0.f;
  rsum[0] = 0.f; rsum[1] = 0.f;

  for (int jt = 0; jt < NL / JS / 64; ++jt) {
    const int j0 = jbase + jt * 64;
    const int jt0 = j0 >> 4;

    // V' frags — issue early, consumed after softmax
    bf16x8 vf[4][2];
#pragma unroll
    for (int dht = 0; dht < 4; ++dht)
#pragma unroll
      for (int jc = 0; jc < 2; ++jc)
        vf[dht][jc] = *(const bf16x8*)(vpb + ((size_t)((j0 >> 5) + jc) * 4 + dht) * 512 + lane * 8);

    // per j-block: S^T = K Q^T (+ bias via ext dims), softmax, b64 P store
#pragma unroll
    for (int jb = 0; jb < 4; ++jb) {
      bf16x8 kf0 = *(const bf16x8*)(kpb + ((size_t)(jt0 + jb) * 2 + 0) * 512 + lane * 8);
      bf16x8 kf1 = *(const bf16x8*)(kpb + ((size_t)(jt0 + jb) * 2 + 1) * 512 + lane * 8);
      bf16x8 kfe = *(const bf16x8*)(kebb + (size_t)(jt0 + jb) * 512 + lane * 8);
#pragma unroll
      for (int ib = 0; ib < 2; ++ib) {
        f32x4 accS;
#pragma unroll
        for (int z = 0; z < 4; ++z) accS[z] = 0.f;
        accS = __builtin_amdgcn_mfma_f32_16x16x32_bf16(kf0, qf[ib][0], accS, 0, 0, 0);
        accS = __builtin_amdgcn_mfma_f32_16x16x32_bf16(kf1, qf[ib][1], accS, 0, 0, 0);
        accS = __builtin_amdgcn_mfma_f32_16x16x32_bf16(kfe, qfe[ib], accS, 0, 0, 0);
        float p0 = fexp2(accS[0] + CBL);
        float p1 = fexp2(accS[1] + CBL);
        float p2 = fexp2(accS[2] + CBL);
        float p3 = fexp2(accS[3] + CBL);
        rsum[ib] += (p0 + p1) + (p2 + p3);
        uint2 w;
        w.x = (uint32_t)f2bf(p0) | ((uint32_t)f2bf(p1) << 16);
        w.y = (uint32_t)f2bf(p2) | ((uint32_t)f2bf(p3) << 16);
        *(uint2*)&Ps[wid * 32 + ib * 16 + l15][jb * 16 + quad * 4] = w;
      }
    }

    // O^T += V^T P^T (wave-private Ps rows; same-wave lgkm ordering)
    bf16x8 pf[2][2];
#pragma unroll
    for (int ib = 0; ib < 2; ++ib)
#pragma unroll
      for (int jc = 0; jc < 2; ++jc)
        pf[ib][jc] = *(const bf16x8*)&Ps[wid * 32 + ib * 16 + l15][jc * 32 + quad * 8];
#pragma unroll
    for (int dht = 0; dht < 4; ++dht)
#pragma unroll
      for (int ib = 0; ib < 2; ++ib) {
        accO[dht][ib] = __builtin_amdgcn_mfma_f32_16x16x32_bf16(vf[dht][0], pf[ib][0], accO[dht][ib], 0, 0, 0);
        accO[dht][ib] = __builtin_amdgcn_mfma_f32_16x16x32_bf16(vf[dht][1], pf[ib][1], accO[dht][ib], 0, 0, 0);
      }
  }

  // ---- epilogue: unnormalized partials (bf16 accO, f32 rsum) ----
  const size_t rgbase = bh * NL + i0;
  const size_t poff = (size_t)js * RG_TOT * DH;
#pragma unroll
  for (int ib = 0; ib < 2; ++ib) {
    float v = rsum[ib];
    v += __shfl_xor(v, 16);
    v += __shfl_xor(v, 32);
    int irow = wid * 32 + ib * 16 + l15;
    if (quad == 0)
      rsbuf[(size_t)js * RG_TOT + rgbase + irow] = v;
#pragma unroll
    for (int dht = 0; dht < 4; ++dht) {
      ushort4 o;
      o.x = f2bf(accO[dht][ib][0]);
      o.y = f2bf(accO[dht][ib][1]);
      o.z = f2bf(accO[dht][ib][2]);
      o.w = f2bf(accO[dht][ib][3]);
      *(ushort4*)&Pb[poff + (rgbase + irow) * DH + dht * 16 + quad * 4] = o;
    }
  }
}

// ---------------------------------------------------------------------------
// Combine split-j partials (JS, bf16) -> bf16 attn [b, l, h*64+dh]
// ---------------------------------------------------------------------------
__global__ __launch_bounds__(256) void combine_kernel(const unsigned short* __restrict__ Pb,
                                                      const float* __restrict__ rsbuf,
                                                      unsigned short* __restrict__ attnb) {
  int idx = blockIdx.x * 256 + threadIdx.x;       // over RG_TOT*16 ushort4 chunks
  int rg = idx >> 4, c4 = idx & 15;
  float s0 = 0.f, s1 = 0.f, s2 = 0.f, s3 = 0.f, rsum = 0.f;
#pragma unroll
  for (int js = 0; js < JS; ++js) {
    ushort4 u = *(const ushort4*)&Pb[((size_t)js * RG_TOT + rg) * DH + c4 * 4];
    s0 += bf2f(u.x); s1 += bf2f(u.y); s2 += bf2f(u.z); s3 += bf2f(u.w);
    rsum += rsbuf[(size_t)js * RG_TOT + rg];
  }
  float rs = 1.0f / rsum;
  int bhm = rg >> 11;           // b*8+h
  int l   = rg & 2047;
  int bb  = bhm >> 3, hh = bhm & 7;
  ushort4 o;
  o.x = f2bf(s0 * rs);
  o.y = f2bf(s1 * rs);
  o.z = f2bf(s2 * rs);
  o.w = f2bf(s3 * rs);
  *(ushort4*)&attnb[(((size_t)bb * NL + l) * ND) + hh * DH + c4 * 4] = o;
}

// ---------------------------------------------------------------------------
// Output GEMM, 64x64 tiles (512 blocks = 2/CU, 8 waves/CU — the 256-block
// 64x128 version ran at 0.5 waves/SIMD). A=w_out rows, B=attn tokens.
// ---------------------------------------------------------------------------
__global__ __launch_bounds__(256, 2) void gemm_out(
    const unsigned short* __restrict__ A, const unsigned short* __restrict__ Bm,
    const float* __restrict__ bias, float* __restrict__ out)
{
  __shared__ __align__(16) unsigned short S[64 * 32 + 64 * 32];  // A | B
  const int tid = threadIdx.x, wid = tid >> 6, lane = tid & 63;
  const int quad = lane >> 4, l15 = lane & 15;
  const int m0 = blockIdx.x * 64, n0 = blockIdx.y * 64;
  const int wm = (wid >> 1) * 32, wn = (wid & 1) * 32;

  f32x4 acc[2][2];
#pragma unroll
  for (int a = 0; a < 2; ++a)
#pragma unroll
    for (int b = 0; b < 2; ++b)
#pragma unroll
      for (int z = 0; z < 4; ++z) acc[a][b][z] = 0.f;

  for (int k0 = 0; k0 < ND; k0 += 32) {
#pragma unroll
    for (int p = 0; p < 2; ++p) {
      int c = p * 256 + wid * 64 + lane;   // 512 chunks: A 256 | B 256
      if (c < 256) {
        int row = c >> 2, off = c & 3;
        gl_lds16(A + (size_t)(m0 + row) * ND + k0 + off * 8, &S[c * 8]);
      } else {
        int cb = c - 256;
        int row = cb >> 2, off = cb & 3;
        gl_lds16(Bm + (size_t)(n0 + row) * ND + k0 + off * 8, &S[2048 + cb * 8]);
      }
    }
    __syncthreads();
    bf16x8 af[2], bfr[2];
#pragma unroll
    for (int mb = 0; mb < 2; ++mb)
      af[mb] = *(const bf16x8*)&S[(wm + mb * 16 + l15) * 32 + quad * 8];
#pragma unroll
    for (int nb = 0; nb < 2; ++nb)
      bfr[nb] = *(const bf16x8*)&S[2048 + (wn + nb * 16 + l15) * 32 + quad * 8];
#pragma unroll
    for (int mb = 0; mb < 2; ++mb)
#pragma unroll
      for (int nb = 0; nb < 2; ++nb)
        acc[mb][nb] = __builtin_amdgcn_mfma_f32_16x16x32_bf16(af[mb], bfr[nb], acc[mb][nb], 0, 0, 0);
    __syncthreads();
  }

#pragma unroll
  for (int mb = 0; mb < 2; ++mb) {
    int e0 = m0 + wm + mb * 16 + quad * 4;
    float4 bv = *(const float4*)&bias[e0];
#pragma unroll
    for (int nb = 0; nb < 2; ++nb) {
      int token = n0 + wn + nb * 16 + l15;
      float4 o;
      o.x = acc[mb][nb][0] + bv.x;
      o.y = acc[mb][nb][1] + bv.y;
      o.z = acc[mb][nb][2] + bv.z;
      o.w = acc[mb][nb][3] + bv.w;
      *(float4*)&out[(size_t)token * ND + e0] = o;
    }
  }
}

// ---------------------------------------------------------------------------
extern "C" void kernel_launch(void* const* d_in, const int* in_sizes, int n_in,
                              void* d_out, int out_size, void* d_ws, size_t ws_size,
                              hipStream_t stream) {
  const float* x         = (const float*)d_in[0];
  const float* positions = (const float*)d_in[1];
  const float* w_qkv     = (const float*)d_in[2];
  const float* w_out     = (const float*)d_in[3];
  const float* b_out     = (const float*)d_in[4];
  const float* log_sigma = (const float*)d_in[5];
  const float* gbias     = (const float*)d_in[6];
  const int*   ns        = (const int*)d_in[7];

  // workspace layout (shorts unless noted); lifetime overlap:
  //   region R: [wqb] (dead after gemm_qkv) overlapped by [Pb | rsbuf]
  //   xb (x bf16) dead after gemm_qkv -> reused as attn bf16
  unsigned short* ws   = (unsigned short*)d_ws;
  unsigned short* xb   = ws;                   // 2,097,152
  unsigned short* wob  = xb   + 2097152;       //   262,144
  unsigned short* qbf  = wob  + 262144;        // 2,097,152
  unsigned short* kpf  = qbf  + 2097152;       // 2,097,152 (K' frag-major)
  unsigned short* vpf  = kpf  + 2097152;       // 2,097,152 (V' frag-major)
  unsigned short* qext = vpf  + 2097152;       // 1,048,576
  unsigned short* kext = qext + 1048576;       // 1,048,576
  unsigned short* R    = kext + 1048576;
  unsigned short* wqb  = R;                    //   786,432
  unsigned short* Pb   = R;                    // JS*32768*64 bf16 = 16.8 MB
  float* rsbuf = (float*)(Pb + (size_t)JS * RG_TOT * DH);  // JS*32768 f32

  // 1) f32 -> bf16 + bias-ext builders (k_ext, q_ext)
  cvt_ext<<<(TOTC + 65536) / 256, 256, 0, stream>>>(
      x, w_qkv, w_out, positions, log_sigma, gbias, ns, xb, wqb, wob, kext, qext);

  // 2) QKV projection (128x64 tiles, 768 blocks) -> q, K', V'
  dim3 g1((3 * NH * DH) / 128, NB * NL / 64);
  gemm_qkv<<<g1, 256, 0, stream>>>(wqb, xb, qbf, kpf, vpf);

  // 3) flash attention partials (split-j=4, barrier-free, ext-bias MFMA)
  dim3 g2((NL / 128) * JS, NH, NB);
  flash_kernel<<<g2, 256, 0, stream>>>(qbf, qext, kpf, kext, vpf, gbias, Pb, rsbuf);

  // 4) combine -> bf16 attn (into xb; reads partials exactly once)
  combine_kernel<<<RG_TOT * 16 / 256, 256, 0, stream>>>(Pb, rsbuf, xb);

  // 5) output projection (64x64 tiles, 512 blocks) + bias -> f32 d_out
  dim3 g3(ND / 64, NB * NL / 64);
  gemm_out<<<g3, 256, 0, stream>>>(wob, xb, b_out, (float*)d_out);
}

// Round 13
// 142.905 us; speedup vs baseline: 1.1683x; 1.0084x over previous
//
#include <hip/hip_runtime.h>
#include <stdint.h>
#include <stddef.h>

// Problem constants (fixed by setup_inputs)
#define NB   2      // batch
#define NL   2048   // seq len
#define ND   512    // model dim
#define NH   8      // heads
#define DH   64     // dim head
#define LOG2E 1.44269504f
#define RG_TOT 32768  // NB*NH*NL rows of partials
#define JS   4      // split-j factor

typedef __attribute__((ext_vector_type(8))) short bf16x8;
typedef __attribute__((ext_vector_type(4))) float f32x4;

__device__ __forceinline__ unsigned short f2bf(float f) {
  union { float f; unsigned int u; } c; c.f = f;
  unsigned int u = c.u;
  unsigned int r = u + 0x7fffu + ((u >> 16) & 1u);
  return (unsigned short)(r >> 16);
}

__device__ __forceinline__ float bf2f(unsigned short u) {
  union { unsigned int i; float f; } c; c.i = ((unsigned int)u) << 16; return c.f;
}

// hi/lo bf16 split: hi+lo == v to ~2^-16 relative
__device__ __forceinline__ void split2(float v, unsigned short& h, unsigned short& l) {
  h = f2bf(v);
  l = f2bf(v - bf2f(h));
}

__device__ __forceinline__ float fexp2(float x) {
#if __has_builtin(__builtin_amdgcn_exp2f)
  return __builtin_amdgcn_exp2f(x);
#else
  return exp2f(x);
#endif
}

// async global->LDS 16B copy; lanes of a wave must target base + lane*16
__device__ __forceinline__ void gl_lds16(const unsigned short* g, unsigned short* l) {
#if __has_builtin(__builtin_amdgcn_global_load_lds)
  __builtin_amdgcn_global_load_lds(
      (const __attribute__((address_space(1))) unsigned int*)g,
      (__attribute__((address_space(3))) unsigned int*)l, 16, 0, 0);
#else
  *(uint4*)l = *(const uint4*)g;
#endif
}

// ---------------------------------------------------------------------------
// cvt + ext-bias builders.
// Section A: f32->bf16 for x, w_qkv, w_out.
// Section B: k_ext frag-major; Section C: q_ext row-major.
// Bias bilinear decomposition (log2 units), CI=log2e/(2 sig^2), LGB=log2e*gb:
//   d0,1: a=split(riCm)   b=1,1        (riCm=-CI|pi|^2-LGB, zeroed if i>=Ls)
//   d2,3: a=1,1           b=split(rjC) (rjC=-CI|pj|^2, zeroed if j>=Ls)
//   d4,5,6: a=(xh,xl,xh)  b=(Xh,Xh,Xl) (x=pix, X=2CI*pjx)
//   d7,8,9: same for y;   dims 10..31 zero
// ---------------------------------------------------------------------------
#define XC  524288   // 4096*512/4
#define WQC 196608   // 1536*512/4
#define WOC 65536    // 512*512/4
#define TOTC (XC + WQC + WOC)
__global__ void cvt_ext(const float* __restrict__ x, const float* __restrict__ wq,
                        const float* __restrict__ wo, const float* __restrict__ positions,
                        const float* __restrict__ log_sigma, const float* __restrict__ gbias_p,
                        const int* __restrict__ ns_p,
                        unsigned short* __restrict__ xb, unsigned short* __restrict__ wqb,
                        unsigned short* __restrict__ wob,
                        unsigned short* __restrict__ kext, unsigned short* __restrict__ qext) {
  int idx = blockIdx.x * 256 + threadIdx.x;
  if (idx < TOTC) {
    const float* src; unsigned short* dst; int off;
    if (idx < XC)            { src = x;  dst = xb;  off = idx; }
    else if (idx < XC + WQC) { src = wq; dst = wqb; off = idx - XC; }
    else                     { src = wo; dst = wob; off = idx - XC - WQC; }
    float4 f = ((const float4*)src)[off];
    ushort4 o;
    o.x = f2bf(f.x); o.y = f2bf(f.y); o.z = f2bf(f.z); o.w = f2bf(f.w);
    ((ushort4*)dst)[off] = o;
    return;
  }
  int t2 = idx - TOTC;          // [0, 65536)
  int bh = (t2 >> 11) & 15;
  int j  = t2 & 2047;
  int b  = bh >> 3, h = bh & 7;
  int Ls = ns_p[0];
  float sig = __expf(log_sigma[h]);
  float CI  = LOG2E * 0.5f / (sig * sig);
  uint4 z = make_uint4(0u, 0u, 0u, 0u);
  if (t2 < 32768) {
    // Section B: k_ext
    unsigned short bv[16];
#pragma unroll
    for (int q = 0; q < 16; ++q) bv[q] = 0;
    if (j < Ls) {
      float px = positions[((size_t)b * Ls + j) * 2];
      float py = positions[((size_t)b * Ls + j) * 2 + 1];
      float rjC = -(CI * (px * px + py * py));
      unsigned short one = f2bf(1.0f);
      bv[0] = one; bv[1] = one;
      split2(rjC, bv[2], bv[3]);
      unsigned short Xh, Xl, Yh, Yl;
      split2(2.0f * CI * px, Xh, Xl);
      split2(2.0f * CI * py, Yh, Yl);
      bv[4] = Xh; bv[5] = Xh; bv[6] = Xl;
      bv[7] = Yh; bv[8] = Yh; bv[9] = Yl;
    }
    unsigned short* kx = kext + ((size_t)bh * 128 + (j >> 4)) * 512 + (size_t)(j & 15) * 8;
    *(uint4*)(kx)       = *(uint4*)&bv[0];
    *(uint4*)(kx + 128) = *(uint4*)&bv[8];
    *(uint4*)(kx + 256) = z;
    *(uint4*)(kx + 384) = z;
  } else {
    // Section C: q_ext
    unsigned short av[16];
#pragma unroll
    for (int q = 0; q < 16; ++q) av[q] = 0;
    if (j < Ls) {
      float px = positions[((size_t)b * Ls + j) * 2];
      float py = positions[((size_t)b * Ls + j) * 2 + 1];
      float LGB = LOG2E * gbias_p[0];
      float riCm = -(CI * (px * px + py * py)) - LGB;
      unsigned short one = f2bf(1.0f);
      split2(riCm, av[0], av[1]);
      av[2] = one; av[3] = one;
      unsigned short xh, xl, yh, yl;
      split2(px, xh, xl);
      split2(py, yh, yl);
      av[4] = xh; av[5] = xl; av[6] = xh;
      av[7] = yh; av[8] = yl; av[9] = yh;
    }
    unsigned short* qx = qext + ((size_t)bh * NL + j) * 32;
    *(uint4*)(qx)      = *(uint4*)&av[0];
    *(uint4*)(qx + 8)  = *(uint4*)&av[8];
    *(uint4*)(qx + 16) = z;
    *(uint4*)(qx + 24) = z;
  }
}

// ---------------------------------------------------------------------------
// QKV GEMM, 128x64 tiles (768 blocks = 3/CU). A=w_qkv rows, B=tokens.
//   q: pre-scaled by 0.125*log2e, row-major [b,h,l,dh] (ushort4)
//   k: FRAGMENT-MAJOR K': ((bh*128 + jt)*2 + kc)*512 + lane*8 shorts
//   v: FRAGMENT-MAJOR V' (fused repack, direct scalar stores)
// ---------------------------------------------------------------------------
__global__ __launch_bounds__(256, 2) void gemm_qkv(
    const unsigned short* __restrict__ A, const unsigned short* __restrict__ Bm,
    unsigned short* __restrict__ qo, unsigned short* __restrict__ kp,
    unsigned short* __restrict__ vp)
{
  __shared__ __align__(16) unsigned short S[128 * 32 + 64 * 32];  // A | B
  const int tid = threadIdx.x, wid = tid >> 6, lane = tid & 63;
  const int quad = lane >> 4, l15 = lane & 15;
  const int m0 = blockIdx.x * 128, n0 = blockIdx.y * 64;
  const int wm = (wid >> 1) * 64, wn = (wid & 1) * 32;

  f32x4 acc[4][2];
#pragma unroll
  for (int a = 0; a < 4; ++a)
#pragma unroll
    for (int b = 0; b < 2; ++b)
#pragma unroll
      for (int z = 0; z < 4; ++z) acc[a][b][z] = 0.f;

  for (int k0 = 0; k0 < ND; k0 += 32) {
#pragma unroll
    for (int p = 0; p < 3; ++p) {
      int c = p * 256 + wid * 64 + lane;   // 768 chunks: A 512 | B 256
      if (c < 512) {
        int row = c >> 2, off = c & 3;
        gl_lds16(A + (size_t)(m0 + row) * ND + k0 + off * 8, &S[c * 8]);
      } else {
        int cb = c - 512;
        int row = cb >> 2, off = cb & 3;
        gl_lds16(Bm + (size_t)(n0 + row) * ND + k0 + off * 8, &S[4096 + cb * 8]);
      }
    }
    __syncthreads();
    bf16x8 af[4], bfr[2];
#pragma unroll
    for (int mb = 0; mb < 4; ++mb)
      af[mb] = *(const bf16x8*)&S[(wm + mb * 16 + l15) * 32 + quad * 8];
#pragma unroll
    for (int nb = 0; nb < 2; ++nb)
      bfr[nb] = *(const bf16x8*)&S[4096 + (wn + nb * 16 + l15) * 32 + quad * 8];
#pragma unroll
    for (int mb = 0; mb < 4; ++mb)
#pragma unroll
      for (int nb = 0; nb < 2; ++nb)
        acc[mb][nb] = __builtin_amdgcn_mfma_f32_16x16x32_bf16(af[mb], bfr[nb], acc[mb][nb], 0, 0, 0);
    __syncthreads();
  }

  const float QSCALE = 0.125f * LOG2E;
#pragma unroll
  for (int mb = 0; mb < 4; ++mb) {
    int e0 = m0 + wm + mb * 16 + quad * 4;
    int s   = e0 >> 9;
    int hh  = (e0 >> 6) & 7;
    if (s == 1) {
      int kc  = mb >> 1;
      int q_t = ((mb & 1) << 1) + (quad >> 1);
      int par = quad & 1;
#pragma unroll
      for (int nb = 0; nb < 2; ++nb) {
        int token = n0 + wn + nb * 16 + l15;
        int bb = token >> 11, ll = token & 2047;
        int jt = ll >> 4;
        ushort4 o;
        o.x = f2bf(acc[mb][nb][0]);
        o.y = f2bf(acc[mb][nb][1]);
        o.z = f2bf(acc[mb][nb][2]);
        o.w = f2bf(acc[mb][nb][3]);
        size_t addr = (((size_t)(bb * NH + hh) * 128 + jt) * 2 + kc) * 512
                    + (q_t * 16 + l15) * 8 + par * 4;
        *(ushort4*)&kp[addr] = o;
      }
    } else if (s == 2) {
      // fused V' fragment repack
      int dh0 = e0 & 63;
      int dht = dh0 >> 4;
      int dl  = dh0 & 15;         // = quad*4
#pragma unroll
      for (int nb = 0; nb < 2; ++nb) {
        int token = n0 + wn + nb * 16 + l15;
        int bb = token >> 11, ll = token & 2047;
        size_t base = (((size_t)(bb * NH + hh) * 64 + (ll >> 5)) * 4 + dht) * 512
                    + (size_t)(((ll >> 3) & 3)) * 128 + (ll & 7);
#pragma unroll
        for (int r = 0; r < 4; ++r)
          vp[base + (size_t)(dl + r) * 8] = f2bf(acc[mb][nb][r]);
      }
    } else {
      int dh0 = e0 & 63;
#pragma unroll
      for (int nb = 0; nb < 2; ++nb) {
        int token = n0 + wn + nb * 16 + l15;
        int bb = token >> 11, ll = token & 2047;
        ushort4 o;
        o.x = f2bf(acc[mb][nb][0] * QSCALE);
        o.y = f2bf(acc[mb][nb][1] * QSCALE);
        o.z = f2bf(acc[mb][nb][2] * QSCALE);
        o.w = f2bf(acc[mb][nb][3] * QSCALE);
        *(ushort4*)&qo[(((size_t)bb * NH + hh) * NL + ll) * DH + dh0] = o;
      }
    }
  }
}

// ---------------------------------------------------------------------------
// Flash attention: S^T orientation, barrier-free, frag-direct K'/K_ext/V'
// loads, bias folded into a 3rd MFMA. P: b64 stores / b128 loads, wave-
// private LDS. Split-j=JS partials (bf16 accO + f32 rsum).
// GEOMETRY (R13): 512-thread blocks (8 independent waves), 256 q-rows/block.
// Grid 512 blocks = exactly 2 blocks/CU -> 16 waves/CU = 4 waves/SIMD, no
// tail (R12 had 1024x4-wave blocks, 3/SIMD + a 1-block/CU 4th round).
// launch_bounds(512,4): VGPR cap 128 — R8's heavier variant fit 128 natural.
// ---------------------------------------------------------------------------
__global__ __launch_bounds__(512, 4) void flash_kernel(
    const unsigned short* __restrict__ qb, const unsigned short* __restrict__ qeb,
    const unsigned short* __restrict__ kp, const unsigned short* __restrict__ keb,
    const unsigned short* __restrict__ vp, const float* __restrict__ gbias_p,
    unsigned short* __restrict__ Pb, float* __restrict__ rsbuf)
{
  const int it = blockIdx.x >> 2;       // 0..7 (256-row i tiles)
  const int js = blockIdx.x & 3;        // 0..3
  const int h  = blockIdx.y;
  const int b  = blockIdx.z;
  const int i0 = it * 256;
  const int jbase = js * (NL / JS);     // 512 j per block
  const float CBL = -8.0f * LOG2E + LOG2E * gbias_p[0];

  const int tid  = threadIdx.x;
  const int wid  = tid >> 6;      // 0..7
  const int lane = tid & 63;
  const int quad = lane >> 4;
  const int l15  = lane & 15;

  __shared__ __align__(16) unsigned short Ps[256][78];   // wave-private rows

  const size_t bh = (size_t)b * NH + h;
  const unsigned short* qbase  = qb  + (bh * NL + i0 + wid * 32) * DH;
  const unsigned short* qebase = qeb + (bh * NL + i0 + wid * 32) * 32;
  const unsigned short* kpb    = kp  + bh * 131072;
  const unsigned short* kebb   = keb + bh * 65536;
  const unsigned short* vpb    = vp  + bh * 131072;

  // Q B-frags (lane l15 = i) + ext
  bf16x8 qf[2][2], qfe[2];
#pragma unroll
  for (int ib = 0; ib < 2; ++ib) {
#pragma unroll
    for (int kc = 0; kc < 2; ++kc)
      qf[ib][kc] = *(const bf16x8*)(qbase + (size_t)(ib * 16 + l15) * DH + kc * 32 + quad * 8);
    qfe[ib] = *(const bf16x8*)(qebase + (size_t)(ib * 16 + l15) * 32 + quad * 8);
  }

  f32x4 accO[4][2];   // [dht][ib]; C row = dh, col = i
  float rsum[2];
#pragma unroll
  for (int d = 0; d < 4; ++d)
#pragma unroll
    for (int ib = 0; ib < 2; ++ib)
#pragma unroll
      for (int z = 0; z < 4; ++z) accO[d][ib][z] = 0.f;
  rsum[0] = 0.f; rsum[1] = 0.f;

  for (int jt = 0; jt < NL / JS / 64; ++jt) {
    const int j0 = jbase + jt * 64;
    const int jt0 = j0 >> 4;

    // V' frags — issue early, consumed after softmax
    bf16x8 vf[4][2];
#pragma unroll
    for (int dht = 0; dht < 4; ++dht)
#pragma unroll
      for (int jc = 0; jc < 2; ++jc)
        vf[dht][jc] = *(const bf16x8*)(vpb + ((size_t)((j0 >> 5) + jc) * 4 + dht) * 512 + lane * 8);

    // per j-block: S^T = K Q^T (+ bias via ext dims), softmax, b64 P store
#pragma unroll
    for (int jb = 0; jb < 4; ++jb) {
      bf16x8 kf0 = *(const bf16x8*)(kpb + ((size_t)(jt0 + jb) * 2 + 0) * 512 + lane * 8);
      bf16x8 kf1 = *(const bf16x8*)(kpb + ((size_t)(jt0 + jb) * 2 + 1) * 512 + lane * 8);
      bf16x8 kfe = *(const bf16x8*)(kebb + (size_t)(jt0 + jb) * 512 + lane * 8);
#pragma unroll
      for (int ib = 0; ib < 2; ++ib) {
        f32x4 accS;
#pragma unroll
        for (int z = 0; z < 4; ++z) accS[z] = 0.f;
        accS = __builtin_amdgcn_mfma_f32_16x16x32_bf16(kf0, qf[ib][0], accS, 0, 0, 0);
        accS = __builtin_amdgcn_mfma_f32_16x16x32_bf16(kf1, qf[ib][1], accS, 0, 0, 0);
        accS = __builtin_amdgcn_mfma_f32_16x16x32_bf16(kfe, qfe[ib], accS, 0, 0, 0);
        float p0 = fexp2(accS[0] + CBL);
        float p1 = fexp2(accS[1] + CBL);
        float p2 = fexp2(accS[2] + CBL);
        float p3 = fexp2(accS[3] + CBL);
        rsum[ib] += (p0 + p1) + (p2 + p3);
        uint2 w;
        w.x = (uint32_t)f2bf(p0) | ((uint32_t)f2bf(p1) << 16);
        w.y = (uint32_t)f2bf(p2) | ((uint32_t)f2bf(p3) << 16);
        *(uint2*)&Ps[wid * 32 + ib * 16 + l15][jb * 16 + quad * 4] = w;
      }
    }

    // O^T += V^T P^T (wave-private Ps rows; same-wave lgkm ordering)
    bf16x8 pf[2][2];
#pragma unroll
    for (int ib = 0; ib < 2; ++ib)
#pragma unroll
      for (int jc = 0; jc < 2; ++jc)
        pf[ib][jc] = *(const bf16x8*)&Ps[wid * 32 + ib * 16 + l15][jc * 32 + quad * 8];
#pragma unroll
    for (int dht = 0; dht < 4; ++dht)
#pragma unroll
      for (int ib = 0; ib < 2; ++ib) {
        accO[dht][ib] = __builtin_amdgcn_mfma_f32_16x16x32_bf16(vf[dht][0], pf[ib][0], accO[dht][ib], 0, 0, 0);
        accO[dht][ib] = __builtin_amdgcn_mfma_f32_16x16x32_bf16(vf[dht][1], pf[ib][1], accO[dht][ib], 0, 0, 0);
      }
  }

  // ---- epilogue: unnormalized partials (bf16 accO, f32 rsum) ----
  const size_t rgbase = bh * NL + i0;
  const size_t poff = (size_t)js * RG_TOT * DH;
#pragma unroll
  for (int ib = 0; ib < 2; ++ib) {
    float v = rsum[ib];
    v += __shfl_xor(v, 16);
    v += __shfl_xor(v, 32);
    int irow = wid * 32 + ib * 16 + l15;
    if (quad == 0)
      rsbuf[(size_t)js * RG_TOT + rgbase + irow] = v;
#pragma unroll
    for (int dht = 0; dht < 4; ++dht) {
      ushort4 o;
      o.x = f2bf(accO[dht][ib][0]);
      o.y = f2bf(accO[dht][ib][1]);
      o.z = f2bf(accO[dht][ib][2]);
      o.w = f2bf(accO[dht][ib][3]);
      *(ushort4*)&Pb[poff + (rgbase + irow) * DH + dht * 16 + quad * 4] = o;
    }
  }
}

// ---------------------------------------------------------------------------
// Combine split-j partials (JS, bf16) -> bf16 attn [b, l, h*64+dh]
// ---------------------------------------------------------------------------
__global__ __launch_bounds__(256) void combine_kernel(const unsigned short* __restrict__ Pb,
                                                      const float* __restrict__ rsbuf,
                                                      unsigned short* __restrict__ attnb) {
  int idx = blockIdx.x * 256 + threadIdx.x;       // over RG_TOT*16 ushort4 chunks
  int rg = idx >> 4, c4 = idx & 15;
  float s0 = 0.f, s1 = 0.f, s2 = 0.f, s3 = 0.f, rsum = 0.f;
#pragma unroll
  for (int js = 0; js < JS; ++js) {
    ushort4 u = *(const ushort4*)&Pb[((size_t)js * RG_TOT + rg) * DH + c4 * 4];
    s0 += bf2f(u.x); s1 += bf2f(u.y); s2 += bf2f(u.z); s3 += bf2f(u.w);
    rsum += rsbuf[(size_t)js * RG_TOT + rg];
  }
  float rs = 1.0f / rsum;
  int bhm = rg >> 11;           // b*8+h
  int l   = rg & 2047;
  int bb  = bhm >> 3, hh = bhm & 7;
  ushort4 o;
  o.x = f2bf(s0 * rs);
  o.y = f2bf(s1 * rs);
  o.z = f2bf(s2 * rs);
  o.w = f2bf(s3 * rs);
  *(ushort4*)&attnb[(((size_t)bb * NL + l) * ND) + hh * DH + c4 * 4] = o;
}

// ---------------------------------------------------------------------------
// Output GEMM, 64x64 tiles (512 blocks = 2/CU, 8 waves/CU).
// A=w_out rows, B=attn tokens. global_load_lds staging, float4 epilogue.
// ---------------------------------------------------------------------------
__global__ __launch_bounds__(256, 2) void gemm_out(
    const unsigned short* __restrict__ A, const unsigned short* __restrict__ Bm,
    const float* __restrict__ bias, float* __restrict__ out)
{
  __shared__ __align__(16) unsigned short S[64 * 32 + 64 * 32];  // A | B
  const int tid = threadIdx.x, wid = tid >> 6, lane = tid & 63;
  const int quad = lane >> 4, l15 = lane & 15;
  const int m0 = blockIdx.x * 64, n0 = blockIdx.y * 64;
  const int wm = (wid >> 1) * 32, wn = (wid & 1) * 32;

  f32x4 acc[2][2];
#pragma unroll
  for (int a = 0; a < 2; ++a)
#pragma unroll
    for (int b = 0; b < 2; ++b)
#pragma unroll
      for (int z = 0; z < 4; ++z) acc[a][b][z] = 0.f;

  for (int k0 = 0; k0 < ND; k0 += 32) {
#pragma unroll
    for (int p = 0; p < 2; ++p) {
      int c = p * 256 + wid * 64 + lane;   // 512 chunks: A 256 | B 256
      if (c < 256) {
        int row = c >> 2, off = c & 3;
        gl_lds16(A + (size_t)(m0 + row) * ND + k0 + off * 8, &S[c * 8]);
      } else {
        int cb = c - 256;
        int row = cb >> 2, off = cb & 3;
        gl_lds16(Bm + (size_t)(n0 + row) * ND + k0 + off * 8, &S[2048 + cb * 8]);
      }
    }
    __syncthreads();
    bf16x8 af[2], bfr[2];
#pragma unroll
    for (int mb = 0; mb < 2; ++mb)
      af[mb] = *(const bf16x8*)&S[(wm + mb * 16 + l15) * 32 + quad * 8];
#pragma unroll
    for (int nb = 0; nb < 2; ++nb)
      bfr[nb] = *(const bf16x8*)&S[2048 + (wn + nb * 16 + l15) * 32 + quad * 8];
#pragma unroll
    for (int mb = 0; mb < 2; ++mb)
#pragma unroll
      for (int nb = 0; nb < 2; ++nb)
        acc[mb][nb] = __builtin_amdgcn_mfma_f32_16x16x32_bf16(af[mb], bfr[nb], acc[mb][nb], 0, 0, 0);
    __syncthreads();
  }

#pragma unroll
  for (int mb = 0; mb < 2; ++mb) {
    int e0 = m0 + wm + mb * 16 + quad * 4;
    float4 bv = *(const float4*)&bias[e0];
#pragma unroll
    for (int nb = 0; nb < 2; ++nb) {
      int token = n0 + wn + nb * 16 + l15;
      float4 o;
      o.x = acc[mb][nb][0] + bv.x;
      o.y = acc[mb][nb][1] + bv.y;
      o.z = acc[mb][nb][2] + bv.z;
      o.w = acc[mb][nb][3] + bv.w;
      *(float4*)&out[(size_t)token * ND + e0] = o;
    }
  }
}

// ---------------------------------------------------------------------------
extern "C" void kernel_launch(void* const* d_in, const int* in_sizes, int n_in,
                              void* d_out, int out_size, void* d_ws, size_t ws_size,
                              hipStream_t stream) {
  const float* x         = (const float*)d_in[0];
  const float* positions = (const float*)d_in[1];
  const float* w_qkv     = (const float*)d_in[2];
  const float* w_out     = (const float*)d_in[3];
  const float* b_out     = (const float*)d_in[4];
  const float* log_sigma = (const float*)d_in[5];
  const float* gbias     = (const float*)d_in[6];
  const int*   ns        = (const int*)d_in[7];

  // workspace layout (shorts unless noted); lifetime overlap:
  //   region R: [wqb] (dead after gemm_qkv) overlapped by [Pb | rsbuf]
  //   xb (x bf16) dead after gemm_qkv -> reused as attn bf16
  unsigned short* ws   = (unsigned short*)d_ws;
  unsigned short* xb   = ws;                   // 2,097,152
  unsigned short* wob  = xb   + 2097152;       //   262,144
  unsigned short* qbf  = wob  + 262144;        // 2,097,152
  unsigned short* kpf  = qbf  + 2097152;       // 2,097,152 (K' frag-major)
  unsigned short* vpf  = kpf  + 2097152;       // 2,097,152 (V' frag-major)
  unsigned short* qext = vpf  + 2097152;       // 1,048,576
  unsigned short* kext = qext + 1048576;       // 1,048,576
  unsigned short* R    = kext + 1048576;
  unsigned short* wqb  = R;                    //   786,432
  unsigned short* Pb   = R;                    // JS*32768*64 bf16 = 16.8 MB
  float* rsbuf = (float*)(Pb + (size_t)JS * RG_TOT * DH);  // JS*32768 f32

  // 1) f32 -> bf16 + bias-ext builders (k_ext, q_ext)
  cvt_ext<<<(TOTC + 65536) / 256, 256, 0, stream>>>(
      x, w_qkv, w_out, positions, log_sigma, gbias, ns, xb, wqb, wob, kext, qext);

  // 2) QKV projection (128x64 tiles, 768 blocks) -> q, K', V'
  dim3 g1((3 * NH * DH) / 128, NB * NL / 64);
  gemm_qkv<<<g1, 256, 0, stream>>>(wqb, xb, qbf, kpf, vpf);

  // 3) flash attention partials (split-j=4, 512-thr blocks, 4 waves/SIMD)
  dim3 g2((NL / 256) * JS, NH, NB);
  flash_kernel<<<g2, 512, 0, stream>>>(qbf, qext, kpf, kext, vpf, gbias, Pb, rsbuf);

  // 4) combine -> bf16 attn (into xb; reads partials exactly once)
  combine_kernel<<<RG_TOT * 16 / 256, 256, 0, stream>>>(Pb, rsbuf, xb);

  // 5) output projection (64x64 tiles, 512 blocks) + bias -> f32 d_out
  dim3 g3(ND / 64, NB * NL / 64);
  gemm_out<<<g3, 256, 0, stream>>>(wob, xb, b_out, (float*)d_out);
}